// Round 2
// baseline (579.763 us; speedup 1.0000x reference)
//
#include <hip/hip_runtime.h>
#include <hip/hip_bf16.h>

#define SEQ   2048
#define NBAT  4
#define NH    12
#define HD    64
#define CDIM  768
#define HID   3072
#define NTOK  (SEQ*NBAT)   // 8192 rows

typedef __attribute__((ext_vector_type(8))) short short8;   // 8 bf16 (4 VGPRs)
typedef __attribute__((ext_vector_type(4))) float floatx4;  // MFMA C/D

__device__ __forceinline__ float bf2f(unsigned short u) {
    union { unsigned int i; float f; } v; v.i = ((unsigned int)u) << 16; return v.f;
}
__device__ __forceinline__ unsigned short f2bf(float f) {
    union { float f; unsigned int i; } v; v.f = f;
    unsigned int i = v.i;
    return (unsigned short)((i + 0x7FFFu + ((i >> 16) & 1u)) >> 16);  // RNE
}

// ---------------------------------------------------------------------------
// fp32 -> bf16 weight conversion (once per call; ~21 MB total, ~5 us)
// ---------------------------------------------------------------------------
__global__ __launch_bounds__(256) void cvt_kernel(
    const float* __restrict__ src, unsigned short* __restrict__ dst)
{
    int i = (blockIdx.x * 256 + threadIdx.x) * 4;
    float4 f = *(const float4*)(src + i);
    ushort4 o;
    o.x = f2bf(f.x); o.y = f2bf(f.y); o.z = f2bf(f.z); o.w = f2bf(f.w);
    *(ushort4*)(dst + i) = o;
}

// ---------------------------------------------------------------------------
// LayerNorm: fp32 in, bf16 out. One wave per 768-elem row, 12 elems/lane.
// ---------------------------------------------------------------------------
__global__ __launch_bounds__(256) void ln_kernel(
    const float* __restrict__ x, const float* __restrict__ w,
    const float* __restrict__ b, unsigned short* __restrict__ y)
{
    int row  = blockIdx.x * 4 + (threadIdx.x >> 6);
    int lane = threadIdx.x & 63;
    const float* xr = x + (size_t)row * CDIM;
    float v[12];
    float s = 0.f, sq = 0.f;
#pragma unroll
    for (int i = 0; i < 12; i++) {
        float f = xr[lane + i * 64];
        v[i] = f; s += f; sq += f * f;
    }
#pragma unroll
    for (int o = 32; o > 0; o >>= 1) {
        s  += __shfl_xor(s,  o, 64);
        sq += __shfl_xor(sq, o, 64);
    }
    float mean = s * (1.f / CDIM);
    float var  = sq * (1.f / CDIM) - mean * mean;
    float rstd = rsqrtf(var + 1e-5f);
    unsigned short* yr = y + (size_t)row * CDIM;
#pragma unroll
    for (int i = 0; i < 12; i++) {
        int c = lane + i * 64;
        yr[c] = f2bf((v[i] - mean) * rstd * w[c] + b[c]);
    }
}

// ---------------------------------------------------------------------------
// GEMM: C[M,N] = act(A[M,K] @ W[N,K]^T + bias + residual)
// A, W bf16; bias/res fp32; out bf16 (OUT32=0) or fp32 (OUT32=1).
// 128x128 tile, BK=32, 4 waves x (64x64 = 4x4 MFMA 16x16x32_bf16).
// A-frag: A[m=lane&15][k=quad*8+j]; B-frag: W[n=lane&15][k=quad*8+j];
// D: row=quad*4+r, col=lane&15  (m89/m91-verified layouts).
// ---------------------------------------------------------------------------
#define BM 128
#define BN 128
#define BK 32
#define LDT 40   // padded LDS leading dim (elems); 80 B stride, 16B-aligned

template<int ACT, int OUT32>
__global__ __launch_bounds__(256) void gemm_bt(
    const unsigned short* __restrict__ A, const unsigned short* __restrict__ W,
    const float* __restrict__ bias, const float* __restrict__ res,
    void* __restrict__ Cv, int M, int N, int K)
{
    __shared__ __align__(16) unsigned short As[BM * LDT];
    __shared__ __align__(16) unsigned short Bs[BN * LDT];
    int tid  = threadIdx.x;
    int wave = tid >> 6, lane = tid & 63;
    int wr = wave >> 1, wc = wave & 1;
    int quad = lane >> 4, l15 = lane & 15;
    int m0 = blockIdx.y * BM, n0 = blockIdx.x * BN;

    floatx4 acc[4][4];
    floatx4 fz = {0.f, 0.f, 0.f, 0.f};
#pragma unroll
    for (int i = 0; i < 4; i++)
#pragma unroll
        for (int j = 0; j < 4; j++) acc[i][j] = fz;

    int srow = tid >> 2;            // 0..63
    int scol = (tid & 3) * 8;       // 0,8,16,24

    for (int k0 = 0; k0 < K; k0 += BK) {
        uint4 a0 = *(const uint4*)(A + (size_t)(m0 + srow)      * K + k0 + scol);
        uint4 a1 = *(const uint4*)(A + (size_t)(m0 + 64 + srow) * K + k0 + scol);
        uint4 b0 = *(const uint4*)(W + (size_t)(n0 + srow)      * K + k0 + scol);
        uint4 b1 = *(const uint4*)(W + (size_t)(n0 + 64 + srow) * K + k0 + scol);
        __syncthreads();   // previous iter's LDS readers done
        *(uint4*)(As + srow * LDT + scol)        = a0;
        *(uint4*)(As + (64 + srow) * LDT + scol) = a1;
        *(uint4*)(Bs + srow * LDT + scol)        = b0;
        *(uint4*)(Bs + (64 + srow) * LDT + scol) = b1;
        __syncthreads();

        short8 af[4], bfg[4];
#pragma unroll
        for (int mt = 0; mt < 4; mt++)
            af[mt] = *(const short8*)(As + (wr * 64 + mt * 16 + l15) * LDT + quad * 8);
#pragma unroll
        for (int nt = 0; nt < 4; nt++)
            bfg[nt] = *(const short8*)(Bs + (wc * 64 + nt * 16 + l15) * LDT + quad * 8);
#pragma unroll
        for (int mt = 0; mt < 4; mt++)
#pragma unroll
            for (int nt = 0; nt < 4; nt++)
                acc[mt][nt] = __builtin_amdgcn_mfma_f32_16x16x32_bf16(
                    af[mt], bfg[nt], acc[mt][nt], 0, 0, 0);
    }

#pragma unroll
    for (int mt = 0; mt < 4; mt++) {
#pragma unroll
        for (int nt = 0; nt < 4; nt++) {
            int col = n0 + wc * 64 + nt * 16 + l15;
            float bv = bias ? bias[col] : 0.f;
#pragma unroll
            for (int r = 0; r < 4; r++) {
                int row = m0 + wr * 64 + mt * 16 + quad * 4 + r;
                size_t idx = (size_t)row * N + col;
                float v = acc[mt][nt][r] + bv;
                if (res) v += res[idx];
                if (ACT == 1) v = 0.5f * v * (1.f + erff(v * 0.70710678118654752f));
                if (OUT32) ((float*)Cv)[idx] = v;
                else       ((unsigned short*)Cv)[idx] = f2bf(v);
            }
        }
    }
}

// ---------------------------------------------------------------------------
// Flash attention. qkv (bf16) row stride 2304: [q 768][k 768][v 768],
// head h at cols h*64. scale 0.125. 4 waves/block, 16 q-rows/wave.
// 64 keys/iter: K row-major LDS, V transposed LDS. Online softmax in
// C-layout regs; P -> wave-private LDS -> A-layout frags.
// ---------------------------------------------------------------------------
__global__ __launch_bounds__(256) void attn_kernel(
    const unsigned short* __restrict__ qkv, unsigned short* __restrict__ out)
{
    __shared__ __align__(16) unsigned short Ks[64 * 72];
    __shared__ __align__(16) unsigned short Vt[64 * 72];   // Vt[d][key]
    __shared__ __align__(16) unsigned short Ps[4][16 * 72];

    int tid  = threadIdx.x;
    int wave = tid >> 6, lane = tid & 63;
    int quad = lane >> 4, l15 = lane & 15;
    int bh = blockIdx.y;
    int b  = bh / NH, h = bh % NH;
    size_t base = (size_t)b * SEQ * 2304 + h * 64;
    int qbase = blockIdx.x * 64 + wave * 16;

    short8 aq[2];
#pragma unroll
    for (int kk = 0; kk < 2; kk++)
        aq[kk] = *(const short8*)(qkv + base + (size_t)(qbase + l15) * 2304 + kk * 32 + quad * 8);

    floatx4 o[4];
    floatx4 fz = {0.f, 0.f, 0.f, 0.f};
#pragma unroll
    for (int dg = 0; dg < 4; dg++) o[dg] = fz;
    float mrow[4], lrow[4];
#pragma unroll
    for (int r = 0; r < 4; r++) { mrow[r] = -1e30f; lrow[r] = 0.f; }

    const unsigned short* kptr = qkv + base + 768;
    const unsigned short* vptr = qkv + base + 1536;

    int skey = tid >> 2;            // K staging: key 0..63
    int sd   = (tid & 3) * 16;      //            d chunk of 16
    int vkey = tid & 63;            // V staging: key 0..63
    int vd0  = wave * 16;           //            wave -> d group

    for (int kt = 0; kt < SEQ; kt += 64) {
        uint4 k0v = *(const uint4*)(kptr + (size_t)(kt + skey) * 2304 + sd);
        uint4 k1v = *(const uint4*)(kptr + (size_t)(kt + skey) * 2304 + sd + 8);
        uint4 v0v = *(const uint4*)(vptr + (size_t)(kt + vkey) * 2304 + vd0);
        uint4 v1v = *(const uint4*)(vptr + (size_t)(kt + vkey) * 2304 + vd0 + 8);
        __syncthreads();   // previous iter's LDS readers done
        *(uint4*)(Ks + skey * 72 + sd)     = k0v;
        *(uint4*)(Ks + skey * 72 + sd + 8) = k1v;
        union { uint4 q[2]; unsigned short u[16]; } vv;
        vv.q[0] = v0v; vv.q[1] = v1v;
#pragma unroll
        for (int i = 0; i < 16; i++)
            Vt[(vd0 + i) * 72 + vkey] = vv.u[i];
        __syncthreads();

        // S = Q K^T
        floatx4 st[4];
#pragma unroll
        for (int t = 0; t < 4; t++) {
            floatx4 s = fz;
#pragma unroll
            for (int kk = 0; kk < 2; kk++) {
                short8 bk = *(const short8*)(Ks + (t * 16 + l15) * 72 + kk * 32 + quad * 8);
                s = __builtin_amdgcn_mfma_f32_16x16x32_bf16(aq[kk], bk, s, 0, 0, 0);
            }
            st[t] = s;
        }

        // online softmax: row = quad*4 + r; 16 lanes of quad hold 64 keys
#pragma unroll
        for (int r = 0; r < 4; r++) {
            float s0 = st[0][r] * 0.125f, s1 = st[1][r] * 0.125f;
            float s2 = st[2][r] * 0.125f, s3 = st[3][r] * 0.125f;
            float tmax = fmaxf(fmaxf(s0, s1), fmaxf(s2, s3));
#pragma unroll
            for (int ofs = 8; ofs >= 1; ofs >>= 1) tmax = fmaxf(tmax, __shfl_xor(tmax, ofs, 64));
            float mnew  = fmaxf(mrow[r], tmax);
            float alpha = __expf(mrow[r] - mnew);
            float p0 = __expf(s0 - mnew), p1 = __expf(s1 - mnew);
            float p2 = __expf(s2 - mnew), p3 = __expf(s3 - mnew);
            float psum = p0 + p1 + p2 + p3;
#pragma unroll
            for (int ofs = 8; ofs >= 1; ofs >>= 1) psum += __shfl_xor(psum, ofs, 64);
            lrow[r] = lrow[r] * alpha + psum;
            mrow[r] = mnew;
#pragma unroll
            for (int dg = 0; dg < 4; dg++) o[dg][r] *= alpha;
            unsigned short* pr = Ps[wave] + (quad * 4 + r) * 72 + l15;
            pr[0]  = f2bf(p0); pr[16] = f2bf(p1);
            pr[32] = f2bf(p2); pr[48] = f2bf(p3);
        }

        // O += P V  (Ps wave-private: no barrier)
#pragma unroll
        for (int half = 0; half < 2; half++) {
            short8 ap = *(const short8*)(Ps[wave] + l15 * 72 + half * 32 + quad * 8);
#pragma unroll
            for (int dg = 0; dg < 4; dg++) {
                short8 bv = *(const short8*)(Vt + (dg * 16 + l15) * 72 + half * 32 + quad * 8);
                o[dg] = __builtin_amdgcn_mfma_f32_16x16x32_bf16(ap, bv, o[dg], 0, 0, 0);
            }
        }
    }

#pragma unroll
    for (int r = 0; r < 4; r++) {
        float inv = 1.f / lrow[r];
        int row = qbase + quad * 4 + r;
        size_t orow = ((size_t)b * SEQ + row) * CDIM + h * 64;
#pragma unroll
        for (int dg = 0; dg < 4; dg++)
            out[orow + dg * 16 + l15] = f2bf(o[dg][r] * inv);
    }
}

// ---------------------------------------------------------------------------
extern "C" void kernel_launch(void* const* d_in, const int* in_sizes, int n_in,
                              void* d_out, int out_size, void* d_ws, size_t ws_size,
                              hipStream_t stream)
{
    const float* x      = (const float*)d_in[0];
    const float* qkv_w  = (const float*)d_in[1];
    const float* proj_w = (const float*)d_in[2];
    const float* proj_b = (const float*)d_in[3];
    const float* n1w    = (const float*)d_in[4];
    const float* n1b    = (const float*)d_in[5];
    const float* n2w    = (const float*)d_in[6];
    const float* n2b    = (const float*)d_in[7];
    const float* fc1w   = (const float*)d_in[8];
    const float* fc1b   = (const float*)d_in[9];
    const float* fc2w   = (const float*)d_in[10];
    const float* fc2b   = (const float*)d_in[11];
    float* out = (float*)d_out;   // also doubles as x2 (post-attn residual, fp32)

    // ws layout (ushort units):
    unsigned short* ws = (unsigned short*)d_ws;
    unsigned short* wq = ws;                    // 3*768*768 = 1,769,472
    unsigned short* wp = wq + 1769472;          //   589,824
    unsigned short* w1 = wp + 589824;           // 2,359,296
    unsigned short* w2 = w1 + 2359296;          // 2,359,296
    unsigned short* h    = w2 + 2359296;        // 8192*768  = 6,291,456
    unsigned short* qkv  = h + 6291456;         // 8192*2304 = 18,874,368
    unsigned short* attn = qkv + 18874368;      // 8192*768  = 6,291,456
    unsigned short* a    = qkv;                 // fc1 out 8192*3072 = qkv+attn reuse
    // total: 38,535,168 ushorts = 77.1 MB

    dim3 blk(256);
    cvt_kernel<<<1769472 / 1024, blk, 0, stream>>>(qkv_w, wq);
    cvt_kernel<<<589824 / 1024,  blk, 0, stream>>>(proj_w, wp);
    cvt_kernel<<<2359296 / 1024, blk, 0, stream>>>(fc1w, w1);
    cvt_kernel<<<2359296 / 1024, blk, 0, stream>>>(fc2w, w2);

    ln_kernel<<<NTOK / 4, blk, 0, stream>>>(x, n1w, n1b, h);
    gemm_bt<0, 0><<<dim3(2304 / BN, NTOK / BM), blk, 0, stream>>>(
        h, wq, nullptr, nullptr, qkv, NTOK, 2304, 768);
    attn_kernel<<<dim3(SEQ / 64, NBAT * NH), blk, 0, stream>>>(qkv, attn);
    gemm_bt<0, 1><<<dim3(768 / BN, NTOK / BM), blk, 0, stream>>>(
        attn, wp, proj_b, x, out, NTOK, 768, 768);          // out = x2 (fp32)
    ln_kernel<<<NTOK / 4, blk, 0, stream>>>(out, n2w, n2b, h);
    gemm_bt<1, 0><<<dim3(3072 / BN, NTOK / BM), blk, 0, stream>>>(
        h, w1, fc1b, nullptr, a, NTOK, 3072, 768);
    gemm_bt<0, 1><<<dim3(768 / BN, NTOK / BM), blk, 0, stream>>>(
        a, w2, fc2b, out, out, NTOK, 768, 3072);            // in-place res: safe
}

// Round 3
// 553.080 us; speedup vs baseline: 1.0482x; 1.0482x over previous
//
#include <hip/hip_runtime.h>
#include <hip/hip_bf16.h>

#define SEQ   2048
#define NBAT  4
#define NH    12
#define HD    64
#define CDIM  768
#define HID   3072
#define NTOK  (SEQ*NBAT)   // 8192 rows

typedef __attribute__((ext_vector_type(8))) short short8;   // 8 bf16 (4 VGPRs)
typedef __attribute__((ext_vector_type(4))) float floatx4;  // MFMA C/D

__device__ __forceinline__ float bf2f(unsigned short u) {
    union { unsigned int i; float f; } v; v.i = ((unsigned int)u) << 16; return v.f;
}
__device__ __forceinline__ unsigned short f2bf(float f) {
    union { float f; unsigned int i; } v; v.f = f;
    unsigned int i = v.i;
    return (unsigned short)((i + 0x7FFFu + ((i >> 16) & 1u)) >> 16);  // RNE
}
__device__ __forceinline__ unsigned int fbits(float f) {
    union { float f; unsigned int i; } v; v.f = f; return v.i;
}
// async global->LDS, 16B/lane; LDS dest = wave-uniform base + lane*16B
__device__ __forceinline__ void gload16(const unsigned short* g, unsigned short* l) {
    __builtin_amdgcn_global_load_lds(
        (const __attribute__((address_space(1))) unsigned int*)g,
        (__attribute__((address_space(3))) unsigned int*)l, 16, 0, 0);
}

// ---------------------------------------------------------------------------
// fp32 -> bf16 weight conversion
// ---------------------------------------------------------------------------
__global__ __launch_bounds__(256) void cvt_kernel(
    const float* __restrict__ src, unsigned short* __restrict__ dst)
{
    int i = (blockIdx.x * 256 + threadIdx.x) * 4;
    float4 f = *(const float4*)(src + i);
    ushort4 o;
    o.x = f2bf(f.x); o.y = f2bf(f.y); o.z = f2bf(f.z); o.w = f2bf(f.w);
    *(ushort4*)(dst + i) = o;
}

// ---------------------------------------------------------------------------
// LayerNorm: fp32 in, bf16 out. One wave per 768-elem row.
// ---------------------------------------------------------------------------
__global__ __launch_bounds__(256) void ln_kernel(
    const float* __restrict__ x, const float* __restrict__ w,
    const float* __restrict__ b, unsigned short* __restrict__ y)
{
    int row  = blockIdx.x * 4 + (threadIdx.x >> 6);
    int lane = threadIdx.x & 63;
    const float* xr = x + (size_t)row * CDIM;
    float v[12];
    float s = 0.f, sq = 0.f;
#pragma unroll
    for (int i = 0; i < 12; i++) {
        float f = xr[lane + i * 64];
        v[i] = f; s += f; sq += f * f;
    }
#pragma unroll
    for (int o = 32; o > 0; o >>= 1) {
        s  += __shfl_xor(s,  o, 64);
        sq += __shfl_xor(sq, o, 64);
    }
    float mean = s * (1.f / CDIM);
    float var  = sq * (1.f / CDIM) - mean * mean;
    float rstd = rsqrtf(var + 1e-5f);
    unsigned short* yr = y + (size_t)row * CDIM;
#pragma unroll
    for (int i = 0; i < 12; i++) {
        int c = lane + i * 64;
        yr[c] = f2bf((v[i] - mean) * rstd * w[c] + b[c]);
    }
}

// ---------------------------------------------------------------------------
// GEMM (m97 structure): C = act(A[M,K] @ W[N,K]^T + bias + residual)
// 128x128 tile, BK=32, global_load_lds width-16 staging into UNPADDED LDS.
// Lane->LDS mapping: lane i -> row i/4, k (i&3)*8 (matches base+lane*16B).
// ---------------------------------------------------------------------------
#define BM 128
#define BN 128
#define BK 32

template<int ACT, int OUT32>
__global__ __launch_bounds__(256) void gemm_bt(
    const unsigned short* __restrict__ A, const unsigned short* __restrict__ W,
    const float* __restrict__ bias, const float* __restrict__ res,
    void* __restrict__ Cv, int M, int N, int K)
{
    __shared__ __align__(16) unsigned short As[BM * BK];   // 8 KB
    __shared__ __align__(16) unsigned short Bs[BN * BK];
    int tid  = threadIdx.x;
    int wave = tid >> 6, lane = tid & 63;
    int wr = wave >> 1, wc = wave & 1;
    int quad = lane >> 4, l15 = lane & 15;
    int m0 = blockIdx.y * BM, n0 = blockIdx.x * BN;

    // wave w stages rows [32w, 32w+32) of A and of W (two 16-row DMA issues each)
    const unsigned short* Ag = A + (size_t)(m0 + wave * 32 + (lane >> 2)) * K + (lane & 3) * 8;
    const unsigned short* Wg = W + (size_t)(n0 + wave * 32 + (lane >> 2)) * K + (lane & 3) * 8;
    unsigned short* AsW = As + wave * 1024;   // 32 rows * 32 elems
    unsigned short* BsW = Bs + wave * 1024;

    floatx4 acc[4][4];
    floatx4 fz = {0.f, 0.f, 0.f, 0.f};
#pragma unroll
    for (int i = 0; i < 4; i++)
#pragma unroll
        for (int j = 0; j < 4; j++) acc[i][j] = fz;

    for (int k0 = 0; k0 < K; k0 += BK) {
        __syncthreads();   // prior readers done before overwrite
        gload16(Ag + k0,                   AsW);
        gload16(Ag + (size_t)16 * K + k0,  AsW + 512);
        gload16(Wg + k0,                   BsW);
        gload16(Wg + (size_t)16 * K + k0,  BsW + 512);
        __syncthreads();   // drains vmcnt(0): DMA visible

        short8 af[4], bfg[4];
#pragma unroll
        for (int mt = 0; mt < 4; mt++)
            af[mt] = *(const short8*)(As + (wr * 64 + mt * 16 + l15) * BK + quad * 8);
#pragma unroll
        for (int nt = 0; nt < 4; nt++)
            bfg[nt] = *(const short8*)(Bs + (wc * 64 + nt * 16 + l15) * BK + quad * 8);
#pragma unroll
        for (int mt = 0; mt < 4; mt++)
#pragma unroll
            for (int nt = 0; nt < 4; nt++)
                acc[mt][nt] = __builtin_amdgcn_mfma_f32_16x16x32_bf16(
                    af[mt], bfg[nt], acc[mt][nt], 0, 0, 0);
    }

#pragma unroll
    for (int mt = 0; mt < 4; mt++) {
#pragma unroll
        for (int nt = 0; nt < 4; nt++) {
            int col = n0 + wc * 64 + nt * 16 + l15;
            float bv = bias ? bias[col] : 0.f;
#pragma unroll
            for (int r = 0; r < 4; r++) {
                int row = m0 + wr * 64 + mt * 16 + quad * 4 + r;
                size_t idx = (size_t)row * N + col;
                float v = acc[mt][nt][r] + bv;
                if (res) v += res[idx];
                if (ACT == 1) v = 0.5f * v * (1.f + erff(v * 0.70710678118654752f));
                if (OUT32) ((float*)Cv)[idx] = v;
                else       ((unsigned short*)Cv)[idx] = f2bf(v);
            }
        }
    }
}

// ---------------------------------------------------------------------------
// Flash attention, VALU-dieted.
// Keys inside a 64-tile are PERMUTED: pk = (key&15)*4 + (key>>4), applied
// identically to P and staged V (softmax/PV invariant under key permutation).
// exp2-domain softmax; per-lane l partials (one reduce at end); lazy rescale.
// ---------------------------------------------------------------------------
#define KS2 0.1803368801111244f   // 0.125 * log2(e)

__global__ __launch_bounds__(256) void attn_kernel(
    const unsigned short* __restrict__ qkv, unsigned short* __restrict__ out)
{
    __shared__ __align__(16) unsigned short Ks[64 * 72];
    __shared__ __align__(16) unsigned short Vt[64 * 72];      // Vt[d][pk]
    __shared__ __align__(16) unsigned short Ps[4][16 * 72];   // [row][pk], wave-private

    int tid  = threadIdx.x;
    int wave = tid >> 6, lane = tid & 63;
    int quad = lane >> 4, l15 = lane & 15;
    int bh = blockIdx.y;
    int b  = bh / NH, h = bh % NH;
    size_t base = (size_t)b * SEQ * 2304 + h * 64;
    int qbase = blockIdx.x * 64 + wave * 16;

    short8 aq[2];
#pragma unroll
    for (int kk = 0; kk < 2; kk++)
        aq[kk] = *(const short8*)(qkv + base + (size_t)(qbase + l15) * 2304 + kk * 32 + quad * 8);

    floatx4 o[4];
    floatx4 fz = {0.f, 0.f, 0.f, 0.f};
#pragma unroll
    for (int dg = 0; dg < 4; dg++) o[dg] = fz;
    float mrow[4], lrow[4];
#pragma unroll
    for (int r = 0; r < 4; r++) { mrow[r] = -3e38f; lrow[r] = 0.f; }

    const unsigned short* kptr = qkv + base + 768;
    const unsigned short* vptr = qkv + base + 1536;

    // K staging: key = tid>>2, d-chunk = (tid&3)*16 (two b128 stores)
    int skey = tid >> 2;
    int sd   = (tid & 3) * 16;
    // V staging: keys a and a+16, 8 d's; pk(a) = (a&15)*4 + (a>>4)
    int va   = (tid & 15) + ((tid >> 4) & 1) * 32;
    int vd8  = wave * 16 + ((tid >> 5) & 1) * 8;
    int vpos = (va & 15) * 4 + (va >> 4);          // even

    for (int kt = 0; kt < SEQ; kt += 64) {
        uint4 k0v = *(const uint4*)(kptr + (size_t)(kt + skey) * 2304 + sd);
        uint4 k1v = *(const uint4*)(kptr + (size_t)(kt + skey) * 2304 + sd + 8);
        uint4 v0v = *(const uint4*)(vptr + (size_t)(kt + va)      * 2304 + vd8);
        uint4 v1v = *(const uint4*)(vptr + (size_t)(kt + va + 16) * 2304 + vd8);
        __syncthreads();
        *(uint4*)(Ks + skey * 72 + sd)     = k0v;
        *(uint4*)(Ks + skey * 72 + sd + 8) = k1v;
        union { uint4 q; unsigned short u[8]; } u0, u1;
        u0.q = v0v; u1.q = v1v;
#pragma unroll
        for (int i = 0; i < 8; i++) {
            unsigned int w = (unsigned int)u0.u[i] | ((unsigned int)u1.u[i] << 16);
            *(unsigned int*)(Vt + (vd8 + i) * 72 + vpos) = w;   // keys a, a+16 -> pk, pk+1
        }
        __syncthreads();

        // S = Q K^T : st[t][r] = score(qrow=quad*4+r, key=t*16+l15)
        floatx4 st[4];
#pragma unroll
        for (int t = 0; t < 4; t++) {
            floatx4 s = fz;
#pragma unroll
            for (int kk = 0; kk < 2; kk++) {
                short8 bk = *(const short8*)(Ks + (t * 16 + l15) * 72 + kk * 32 + quad * 8);
                s = __builtin_amdgcn_mfma_f32_16x16x32_bf16(aq[kk], bk, s, 0, 0, 0);
            }
            st[t] = s;
        }

        // online softmax, base-2 domain
#pragma unroll
        for (int r = 0; r < 4; r++) {
            float s0 = st[0][r] * KS2, s1 = st[1][r] * KS2;
            float s2 = st[2][r] * KS2, s3 = st[3][r] * KS2;
            float tmax = fmaxf(fmaxf(s0, s1), fmaxf(s2, s3));
#pragma unroll
            for (int ofs = 8; ofs >= 1; ofs >>= 1) tmax = fmaxf(tmax, __shfl_xor(tmax, ofs, 64));
            if (tmax > mrow[r]) {                 // quad-uniform branch
                float alpha = exp2f(mrow[r] - tmax);
                mrow[r] = tmax;
                lrow[r] *= alpha;
#pragma unroll
                for (int dg = 0; dg < 4; dg++) o[dg][r] *= alpha;
            }
            float m = mrow[r];
            float p0 = exp2f(s0 - m), p1 = exp2f(s1 - m);
            float p2 = exp2f(s2 - m), p3 = exp2f(s3 - m);
            lrow[r] += (p0 + p1) + (p2 + p3);     // per-lane partial (4 keys/lane)
            // truncate-pack to bf16: pk = l15*4 + t  -> one b64 store
            unsigned int w01 = __builtin_amdgcn_perm(fbits(p1), fbits(p0), 0x07060302);
            unsigned int w23 = __builtin_amdgcn_perm(fbits(p3), fbits(p2), 0x07060302);
            uint2 wv; wv.x = w01; wv.y = w23;
            *(uint2*)(Ps[wave] + (quad * 4 + r) * 72 + l15 * 4) = wv;
        }

        // O += P V  (both in permuted-pk order; Ps wave-private: no barrier)
#pragma unroll
        for (int half = 0; half < 2; half++) {
            short8 ap = *(const short8*)(Ps[wave] + l15 * 72 + half * 32 + quad * 8);
#pragma unroll
            for (int dg = 0; dg < 4; dg++) {
                short8 bv = *(const short8*)(Vt + (dg * 16 + l15) * 72 + half * 32 + quad * 8);
                o[dg] = __builtin_amdgcn_mfma_f32_16x16x32_bf16(ap, bv, o[dg], 0, 0, 0);
            }
        }
    }

    // reduce per-lane l partials across the quad's 16 lanes, then write O/l
#pragma unroll
    for (int r = 0; r < 4; r++) {
#pragma unroll
        for (int ofs = 8; ofs >= 1; ofs >>= 1) lrow[r] += __shfl_xor(lrow[r], ofs, 64);
        float inv = 1.f / lrow[r];
        int row = qbase + quad * 4 + r;
        size_t orow = ((size_t)b * SEQ + row) * CDIM + h * 64;
#pragma unroll
        for (int dg = 0; dg < 4; dg++)
            out[orow + dg * 16 + l15] = f2bf(o[dg][r] * inv);
    }
}

// ---------------------------------------------------------------------------
extern "C" void kernel_launch(void* const* d_in, const int* in_sizes, int n_in,
                              void* d_out, int out_size, void* d_ws, size_t ws_size,
                              hipStream_t stream)
{
    const float* x      = (const float*)d_in[0];
    const float* qkv_w  = (const float*)d_in[1];
    const float* proj_w = (const float*)d_in[2];
    const float* proj_b = (const float*)d_in[3];
    const float* n1w    = (const float*)d_in[4];
    const float* n1b    = (const float*)d_in[5];
    const float* n2w    = (const float*)d_in[6];
    const float* n2b    = (const float*)d_in[7];
    const float* fc1w   = (const float*)d_in[8];
    const float* fc1b   = (const float*)d_in[9];
    const float* fc2w   = (const float*)d_in[10];
    const float* fc2b   = (const float*)d_in[11];
    float* out = (float*)d_out;   // doubles as x2 (post-attn residual, fp32)

    unsigned short* ws = (unsigned short*)d_ws;
    unsigned short* wq = ws;                    // 1,769,472
    unsigned short* wp = wq + 1769472;          //   589,824
    unsigned short* w1 = wp + 589824;           // 2,359,296
    unsigned short* w2 = w1 + 2359296;          // 2,359,296
    unsigned short* h    = w2 + 2359296;        // 6,291,456
    unsigned short* qkv  = h + 6291456;         // 18,874,368
    unsigned short* attn = qkv + 18874368;      // 6,291,456
    unsigned short* a    = qkv;                 // fc1 out reuses qkv+attn

    dim3 blk(256);
    cvt_kernel<<<1769472 / 1024, blk, 0, stream>>>(qkv_w, wq);
    cvt_kernel<<<589824 / 1024,  blk, 0, stream>>>(proj_w, wp);
    cvt_kernel<<<2359296 / 1024, blk, 0, stream>>>(fc1w, w1);
    cvt_kernel<<<2359296 / 1024, blk, 0, stream>>>(fc2w, w2);

    ln_kernel<<<NTOK / 4, blk, 0, stream>>>(x, n1w, n1b, h);
    gemm_bt<0, 0><<<dim3(2304 / BN, NTOK / BM), blk, 0, stream>>>(
        h, wq, nullptr, nullptr, qkv, NTOK, 2304, 768);
    attn_kernel<<<dim3(SEQ / 64, NBAT * NH), blk, 0, stream>>>(qkv, attn);
    gemm_bt<0, 1><<<dim3(768 / BN, NTOK / BM), blk, 0, stream>>>(
        attn, wp, proj_b, x, out, NTOK, 768, 768);
    ln_kernel<<<NTOK / 4, blk, 0, stream>>>(out, n2w, n2b, h);
    gemm_bt<1, 0><<<dim3(3072 / BN, NTOK / BM), blk, 0, stream>>>(
        h, w1, fc1b, nullptr, a, NTOK, 3072, 768);
    gemm_bt<0, 1><<<dim3(768 / BN, NTOK / BM), blk, 0, stream>>>(
        a, w2, fc2b, out, out, NTOK, 768, 3072);
}

// Round 4
// 484.690 us; speedup vs baseline: 1.1962x; 1.1411x over previous
//
#include <hip/hip_runtime.h>
#include <hip/hip_bf16.h>

#define SEQ   2048
#define NBAT  4
#define NH    12
#define HD    64
#define CDIM  768
#define HID   3072
#define NTOK  (SEQ*NBAT)   // 8192 rows

#define KS2 0.1803368801111244f   // 0.125 * log2(e), folded into Q

typedef __attribute__((ext_vector_type(8))) short short8;   // 8 bf16 (4 VGPRs)
typedef __attribute__((ext_vector_type(4))) float floatx4;  // MFMA C/D

__device__ __forceinline__ float bf2f(unsigned short u) {
    union { unsigned int i; float f; } v; v.i = ((unsigned int)u) << 16; return v.f;
}
__device__ __forceinline__ unsigned short f2bf(float f) {
    union { float f; unsigned int i; } v; v.f = f;
    unsigned int i = v.i;
    return (unsigned short)((i + 0x7FFFu + ((i >> 16) & 1u)) >> 16);  // RNE
}
__device__ __forceinline__ unsigned int fbits(float f) {
    union { float f; unsigned int i; } v; v.f = f; return v.i;
}
__device__ __forceinline__ float fast_exp2(float x) {   // native v_exp_f32
#if __has_builtin(__builtin_amdgcn_exp2f)
    return __builtin_amdgcn_exp2f(x);
#else
    return __expf(x * 0.69314718055994531f);
#endif
}
__device__ __forceinline__ float fast_rcp(float x) {
#if __has_builtin(__builtin_amdgcn_rcpf)
    return __builtin_amdgcn_rcpf(x);
#else
    return 1.f / x;
#endif
}
// tanh-form GELU with native ops only (max |err| vs erf-GELU ~1e-3)
__device__ __forceinline__ float gelu_f(float v) {
    float u = 0.7978845608028654f * v * (1.f + 0.044715f * v * v);
    float e = fast_exp2(u * 2.885390081777927f);      // e^(2u)
    float th = 1.f - 2.f * fast_rcp(e + 1.f);         // tanh(u)
    return 0.5f * v * (1.f + th);
}
// async global->LDS, 16B/lane; LDS dest = wave-uniform base + lane*16B
__device__ __forceinline__ void gload16(const unsigned short* g, unsigned short* l) {
    __builtin_amdgcn_global_load_lds(
        (const __attribute__((address_space(1))) unsigned int*)g,
        (__attribute__((address_space(3))) unsigned int*)l, 16, 0, 0);
}

// ---------------------------------------------------------------------------
// fp32 -> bf16 weight conversion
// ---------------------------------------------------------------------------
__global__ __launch_bounds__(256) void cvt_kernel(
    const float* __restrict__ src, unsigned short* __restrict__ dst)
{
    int i = (blockIdx.x * 256 + threadIdx.x) * 4;
    float4 f = *(const float4*)(src + i);
    ushort4 o;
    o.x = f2bf(f.x); o.y = f2bf(f.y); o.z = f2bf(f.z); o.w = f2bf(f.w);
    *(ushort4*)(dst + i) = o;
}

// ---------------------------------------------------------------------------
// LayerNorm: fp32 in, bf16 out. One wave per 768-elem row.
// ---------------------------------------------------------------------------
__global__ __launch_bounds__(256) void ln_kernel(
    const float* __restrict__ x, const float* __restrict__ w,
    const float* __restrict__ b, unsigned short* __restrict__ y)
{
    int row  = blockIdx.x * 4 + (threadIdx.x >> 6);
    int lane = threadIdx.x & 63;
    const float* xr = x + (size_t)row * CDIM;
    float v[12];
    float s = 0.f, sq = 0.f;
#pragma unroll
    for (int i = 0; i < 12; i++) {
        float f = xr[lane + i * 64];
        v[i] = f; s += f; sq += f * f;
    }
#pragma unroll
    for (int o = 32; o > 0; o >>= 1) {
        s  += __shfl_xor(s,  o, 64);
        sq += __shfl_xor(sq, o, 64);
    }
    float mean = s * (1.f / CDIM);
    float var  = sq * (1.f / CDIM) - mean * mean;
    float rstd = rsqrtf(var + 1e-5f);
    unsigned short* yr = y + (size_t)row * CDIM;
#pragma unroll
    for (int i = 0; i < 12; i++) {
        int c = lane + i * 64;
        yr[c] = f2bf((v[i] - mean) * rstd * w[c] + b[c]);
    }
}

// ---------------------------------------------------------------------------
// GEMM (m97 structure): C = act(A[M,K] @ W[N,K]^T + bias + residual)
// cols < scol additionally scaled by `scale` before store (Q pre-scaling).
// ---------------------------------------------------------------------------
#define BM 128
#define BN 128
#define BK 32

template<int ACT, int OUT32>
__global__ __launch_bounds__(256) void gemm_bt(
    const unsigned short* __restrict__ A, const unsigned short* __restrict__ W,
    const float* __restrict__ bias, const float* __restrict__ res,
    void* __restrict__ Cv, int M, int N, int K, int scol, float scale)
{
    __shared__ __align__(16) unsigned short As[BM * BK];   // 8 KB
    __shared__ __align__(16) unsigned short Bs[BN * BK];
    int tid  = threadIdx.x;
    int wave = tid >> 6, lane = tid & 63;
    int wr = wave >> 1, wc = wave & 1;
    int quad = lane >> 4, l15 = lane & 15;
    int m0 = blockIdx.y * BM, n0 = blockIdx.x * BN;

    const unsigned short* Ag = A + (size_t)(m0 + wave * 32 + (lane >> 2)) * K + (lane & 3) * 8;
    const unsigned short* Wg = W + (size_t)(n0 + wave * 32 + (lane >> 2)) * K + (lane & 3) * 8;
    unsigned short* AsW = As + wave * 1024;
    unsigned short* BsW = Bs + wave * 1024;

    floatx4 acc[4][4];
    floatx4 fz = {0.f, 0.f, 0.f, 0.f};
#pragma unroll
    for (int i = 0; i < 4; i++)
#pragma unroll
        for (int j = 0; j < 4; j++) acc[i][j] = fz;

    for (int k0 = 0; k0 < K; k0 += BK) {
        __syncthreads();
        gload16(Ag + k0,                   AsW);
        gload16(Ag + (size_t)16 * K + k0,  AsW + 512);
        gload16(Wg + k0,                   BsW);
        gload16(Wg + (size_t)16 * K + k0,  BsW + 512);
        __syncthreads();

        short8 af[4], bfg[4];
#pragma unroll
        for (int mt = 0; mt < 4; mt++)
            af[mt] = *(const short8*)(As + (wr * 64 + mt * 16 + l15) * BK + quad * 8);
#pragma unroll
        for (int nt = 0; nt < 4; nt++)
            bfg[nt] = *(const short8*)(Bs + (wc * 64 + nt * 16 + l15) * BK + quad * 8);
#pragma unroll
        for (int mt = 0; mt < 4; mt++)
#pragma unroll
            for (int nt = 0; nt < 4; nt++)
                acc[mt][nt] = __builtin_amdgcn_mfma_f32_16x16x32_bf16(
                    af[mt], bfg[nt], acc[mt][nt], 0, 0, 0);
    }

#pragma unroll
    for (int mt = 0; mt < 4; mt++) {
#pragma unroll
        for (int nt = 0; nt < 4; nt++) {
            int col = n0 + wc * 64 + nt * 16 + l15;
            float bv = bias ? bias[col] : 0.f;
            float cs = (col < scol) ? scale : 1.f;
#pragma unroll
            for (int r = 0; r < 4; r++) {
                int row = m0 + wr * 64 + mt * 16 + quad * 4 + r;
                size_t idx = (size_t)row * N + col;
                float v = acc[mt][nt][r] + bv;
                if (res) v += res[idx];
                if (ACT == 1) v = gelu_f(v);
                v *= cs;
                if (OUT32) ((float*)Cv)[idx] = v;
                else       ((unsigned short*)Cv)[idx] = f2bf(v);
            }
        }
    }
}

// ---------------------------------------------------------------------------
// Flash attention, transposed-S form. qkv (bf16) row stride 2304:
// [q 768][k 768][v 768], head h at cols h*64; Q pre-scaled by KS2.
// S^T = K Q^T via mfma(A=K rows, B=Q rows): lane holds 16 scores of q-row
// l15 (keys t*16+quad*4+r) -> in-register max/sum + 2 shuffles per tile.
// P stored [q][key]; V staged transposed natural order; O^T = mfma(V^T, P).
// K/V LDS double-buffered: ONE barrier per tile, t+1 loads overlap compute.
// ---------------------------------------------------------------------------
__global__ __launch_bounds__(256) void attn_kernel(
    const unsigned short* __restrict__ qkv, unsigned short* __restrict__ out)
{
    __shared__ __align__(16) unsigned short Ks[2][64 * 72];
    __shared__ __align__(16) unsigned short Vt[2][64 * 72];   // Vt[d][key]
    __shared__ __align__(16) unsigned short Ps[4][16 * 72];   // [qrow][key]

    int tid  = threadIdx.x;
    int wave = tid >> 6, lane = tid & 63;
    int quad = lane >> 4, l15 = lane & 15;
    int bh = blockIdx.y;
    int b  = bh / NH, h = bh % NH;
    size_t base = (size_t)b * SEQ * 2304 + h * 64;
    int qbase = blockIdx.x * 64 + wave * 16;

    // Q B-frags: B[n=qrow=l15][k=d]  (pre-scaled by KS2)
    short8 bq[2];
#pragma unroll
    for (int kk = 0; kk < 2; kk++)
        bq[kk] = *(const short8*)(qkv + base + (size_t)(qbase + l15) * 2304 + kk * 32 + quad * 8);

    floatx4 o[4];
    floatx4 fz = {0.f, 0.f, 0.f, 0.f};
#pragma unroll
    for (int dg = 0; dg < 4; dg++) o[dg] = fz;
    float m = -3e38f, lsum = 0.f;

    const unsigned short* kptr = qkv + base + 768;
    const unsigned short* vptr = qkv + base + 1536;

    int skey = tid >> 2;            // K staging: key, d-chunk
    int sd   = (tid & 3) * 16;
    int vj   = tid & 31;            // V staging: key pair (2vj, 2vj+1)
    int vd8  = wave * 16 + ((tid >> 5) & 1) * 8;

    // preload tile 0
    uint4 k0v = *(const uint4*)(kptr + (size_t)skey * 2304 + sd);
    uint4 k1v = *(const uint4*)(kptr + (size_t)skey * 2304 + sd + 8);
    uint4 v0v = *(const uint4*)(vptr + (size_t)(2 * vj)     * 2304 + vd8);
    uint4 v1v = *(const uint4*)(vptr + (size_t)(2 * vj + 1) * 2304 + vd8);

    for (int t = 0; t < SEQ / 64; t++) {
        int cur = t & 1;
        unsigned short* K_ = Ks[cur];
        unsigned short* V_ = Vt[cur];
        // write staged regs (overwrite of buf[cur] safe: last read 2 iters ago)
        *(uint4*)(K_ + skey * 72 + sd)     = k0v;
        *(uint4*)(K_ + skey * 72 + sd + 8) = k1v;
        union { uint4 q; unsigned short u[8]; } u0, u1;
        u0.q = v0v; u1.q = v1v;
#pragma unroll
        for (int i = 0; i < 8; i++) {
            unsigned int w = (unsigned int)u0.u[i] | ((unsigned int)u1.u[i] << 16);
            *(unsigned int*)(V_ + (vd8 + i) * 72 + 2 * vj) = w;
        }
        __syncthreads();

        // issue next tile's global loads (overlap with compute below)
        if (t + 1 < SEQ / 64) {
            int kt = (t + 1) * 64;
            k0v = *(const uint4*)(kptr + (size_t)(kt + skey) * 2304 + sd);
            k1v = *(const uint4*)(kptr + (size_t)(kt + skey) * 2304 + sd + 8);
            v0v = *(const uint4*)(vptr + (size_t)(kt + 2 * vj)     * 2304 + vd8);
            v1v = *(const uint4*)(vptr + (size_t)(kt + 2 * vj + 1) * 2304 + vd8);
        }

        // S^T: st[ts][r] = score(key = ts*16 + quad*4 + r, qrow = l15)
        floatx4 st[4];
#pragma unroll
        for (int ts = 0; ts < 4; ts++) {
            floatx4 s = fz;
#pragma unroll
            for (int kk = 0; kk < 2; kk++) {
                short8 ak = *(const short8*)(K_ + (ts * 16 + l15) * 72 + kk * 32 + quad * 8);
                s = __builtin_amdgcn_mfma_f32_16x16x32_bf16(ak, bq[kk], s, 0, 0, 0);
            }
            st[ts] = s;
        }

        // softmax for q-row l15: in-register max over 16, 2 cross-quad shuffles
        float tmax = st[0][0];
#pragma unroll
        for (int ts = 0; ts < 4; ts++)
#pragma unroll
            for (int r = 0; r < 4; r++) tmax = fmaxf(tmax, st[ts][r]);
        tmax = fmaxf(tmax, __shfl_xor(tmax, 16, 64));
        tmax = fmaxf(tmax, __shfl_xor(tmax, 32, 64));
        if (tmax > m) {
            float alpha = fast_exp2(m - tmax);
            m = tmax;
            lsum *= alpha;
#pragma unroll
            for (int dg = 0; dg < 4; dg++)
#pragma unroll
                for (int r = 0; r < 4; r++) o[dg][r] *= alpha;
        }
        float p[4][4];
        float ps = 0.f;
#pragma unroll
        for (int ts = 0; ts < 4; ts++)
#pragma unroll
            for (int r = 0; r < 4; r++) {
                p[ts][r] = fast_exp2(st[ts][r] - m);
                ps += p[ts][r];
            }
        lsum += ps;
        // pack P (bf16 truncation) -> Ps[qrow=l15][key], 4 b64 stores
#pragma unroll
        for (int ts = 0; ts < 4; ts++) {
            unsigned int w01 = __builtin_amdgcn_perm(fbits(p[ts][1]), fbits(p[ts][0]), 0x07060302);
            unsigned int w23 = __builtin_amdgcn_perm(fbits(p[ts][3]), fbits(p[ts][2]), 0x07060302);
            uint2 wv; wv.x = w01; wv.y = w23;
            *(uint2*)(Ps[wave] + l15 * 72 + ts * 16 + quad * 4) = wv;
        }

        // O^T += V^T P : mfma(A=V^T[d][key], B=P[q][key]) -> D[d][q]
#pragma unroll
        for (int half = 0; half < 2; half++) {
            short8 bp = *(const short8*)(Ps[wave] + l15 * 72 + half * 32 + quad * 8);
#pragma unroll
            for (int dg = 0; dg < 4; dg++) {
                short8 av = *(const short8*)(V_ + (dg * 16 + l15) * 72 + half * 32 + quad * 8);
                o[dg] = __builtin_amdgcn_mfma_f32_16x16x32_bf16(av, bp, o[dg], 0, 0, 0);
            }
        }
    }

    // lane's lsum covers its quad's key subsets; combine across quads
    lsum += __shfl_xor(lsum, 16, 64);
    lsum += __shfl_xor(lsum, 32, 64);
    float inv = 1.f / lsum;
    // lane holds O^T[d = dg*16 + quad*4 + r][qrow = l15]
    size_t orow = ((size_t)b * SEQ + qbase + l15) * CDIM + h * 64;
#pragma unroll
    for (int dg = 0; dg < 4; dg++) {
        unsigned int u0 = (unsigned int)f2bf(o[dg][0] * inv) | ((unsigned int)f2bf(o[dg][1] * inv) << 16);
        unsigned int u1 = (unsigned int)f2bf(o[dg][2] * inv) | ((unsigned int)f2bf(o[dg][3] * inv) << 16);
        uint2 wv; wv.x = u0; wv.y = u1;
        *(uint2*)((unsigned short*)out + orow + dg * 16 + quad * 4) = wv;
    }
}

// ---------------------------------------------------------------------------
extern "C" void kernel_launch(void* const* d_in, const int* in_sizes, int n_in,
                              void* d_out, int out_size, void* d_ws, size_t ws_size,
                              hipStream_t stream)
{
    const float* x      = (const float*)d_in[0];
    const float* qkv_w  = (const float*)d_in[1];
    const float* proj_w = (const float*)d_in[2];
    const float* proj_b = (const float*)d_in[3];
    const float* n1w    = (const float*)d_in[4];
    const float* n1b    = (const float*)d_in[5];
    const float* n2w    = (const float*)d_in[6];
    const float* n2b    = (const float*)d_in[7];
    const float* fc1w   = (const float*)d_in[8];
    const float* fc1b   = (const float*)d_in[9];
    const float* fc2w   = (const float*)d_in[10];
    const float* fc2b   = (const float*)d_in[11];
    float* out = (float*)d_out;   // doubles as x2 (post-attn residual, fp32)

    unsigned short* ws = (unsigned short*)d_ws;
    unsigned short* wq = ws;                    // 1,769,472
    unsigned short* wp = wq + 1769472;          //   589,824
    unsigned short* w1 = wp + 589824;           // 2,359,296
    unsigned short* w2 = w1 + 2359296;          // 2,359,296
    unsigned short* h    = w2 + 2359296;        // 6,291,456
    unsigned short* qkv  = h + 6291456;         // 18,874,368
    unsigned short* attn = qkv + 18874368;      // 6,291,456
    unsigned short* a    = qkv;                 // fc1 out reuses qkv+attn

    dim3 blk(256);
    cvt_kernel<<<1769472 / 1024, blk, 0, stream>>>(qkv_w, wq);
    cvt_kernel<<<589824 / 1024,  blk, 0, stream>>>(proj_w, wp);
    cvt_kernel<<<2359296 / 1024, blk, 0, stream>>>(fc1w, w1);
    cvt_kernel<<<2359296 / 1024, blk, 0, stream>>>(fc2w, w2);

    ln_kernel<<<NTOK / 4, blk, 0, stream>>>(x, n1w, n1b, h);
    gemm_bt<0, 0><<<dim3(2304 / BN, NTOK / BM), blk, 0, stream>>>(
        h, wq, nullptr, nullptr, qkv, NTOK, 2304, 768, 768, KS2);   // scale Q cols
    attn_kernel<<<dim3(SEQ / 64, NBAT * NH), blk, 0, stream>>>(qkv, attn);
    gemm_bt<0, 1><<<dim3(768 / BN, NTOK / BM), blk, 0, stream>>>(
        attn, wp, proj_b, x, out, NTOK, 768, 768, 0, 1.f);
    ln_kernel<<<NTOK / 4, blk, 0, stream>>>(out, n2w, n2b, h);
    gemm_bt<1, 0><<<dim3(3072 / BN, NTOK / BM), blk, 0, stream>>>(
        h, w1, fc1b, nullptr, a, NTOK, 3072, 768, 0, 1.f);
    gemm_bt<0, 1><<<dim3(768 / BN, NTOK / BM), blk, 0, stream>>>(
        a, w2, fc2b, out, out, NTOK, 768, 3072, 0, 1.f);
}

// Round 5
// 465.449 us; speedup vs baseline: 1.2456x; 1.0413x over previous
//
#include <hip/hip_runtime.h>
#include <hip/hip_bf16.h>

#define SEQ   2048
#define NBAT  4
#define NH    12
#define HD    64
#define CDIM  768
#define HID   3072
#define NTOK  (SEQ*NBAT)   // 8192 rows

#define KS2 0.1803368801111244f   // 0.125 * log2(e), folded into Q

typedef __attribute__((ext_vector_type(8))) short short8;   // 8 bf16 (4 VGPRs)
typedef __attribute__((ext_vector_type(4))) float floatx4;  // MFMA C/D

__device__ __forceinline__ float bf2f(unsigned short u) {
    union { unsigned int i; float f; } v; v.i = ((unsigned int)u) << 16; return v.f;
}
__device__ __forceinline__ unsigned short f2bf(float f) {
    union { float f; unsigned int i; } v; v.f = f;
    unsigned int i = v.i;
    return (unsigned short)((i + 0x7FFFu + ((i >> 16) & 1u)) >> 16);  // RNE
}
__device__ __forceinline__ unsigned int fbits(float f) {
    union { float f; unsigned int i; } v; v.f = f; return v.i;
}
__device__ __forceinline__ float fast_exp2(float x) {   // native v_exp_f32
#if __has_builtin(__builtin_amdgcn_exp2f)
    return __builtin_amdgcn_exp2f(x);
#else
    return __expf(x * 0.69314718055994531f);
#endif
}
__device__ __forceinline__ float fast_rcp(float x) {
#if __has_builtin(__builtin_amdgcn_rcpf)
    return __builtin_amdgcn_rcpf(x);
#else
    return 1.f / x;
#endif
}
// tanh-form GELU with native ops only
__device__ __forceinline__ float gelu_f(float v) {
    float u = 0.7978845608028654f * v * (1.f + 0.044715f * v * v);
    float e = fast_exp2(u * 2.885390081777927f);      // e^(2u)
    float th = 1.f - 2.f * fast_rcp(e + 1.f);         // tanh(u)
    return 0.5f * v * (1.f + th);
}
// async global->LDS, 16B/lane; LDS dest = wave-uniform base + lane*16B
__device__ __forceinline__ void gload16(const unsigned short* g, unsigned short* l) {
    __builtin_amdgcn_global_load_lds(
        (const __attribute__((address_space(1))) unsigned int*)g,
        (__attribute__((address_space(3))) unsigned int*)l, 16, 0, 0);
}

// ---------------------------------------------------------------------------
// fp32 -> bf16 conversion of all 4 weight matrices in ONE launch.
// Segment sizes in 1024-elem blocks: qkv 1728 | proj 576 | fc1 2304 | fc2 2304
// ---------------------------------------------------------------------------
__global__ __launch_bounds__(256) void cvt_all_kernel(
    const float* __restrict__ s0, const float* __restrict__ s1,
    const float* __restrict__ s2, const float* __restrict__ s3,
    unsigned short* __restrict__ d0, unsigned short* __restrict__ d1,
    unsigned short* __restrict__ d2, unsigned short* __restrict__ d3)
{
    int blk = blockIdx.x;
    const float* src; unsigned short* dst; int off;
    if (blk < 1728)      { src = s0; dst = d0; off = blk; }
    else if (blk < 2304) { src = s1; dst = d1; off = blk - 1728; }
    else if (blk < 4608) { src = s2; dst = d2; off = blk - 2304; }
    else                 { src = s3; dst = d3; off = blk - 4608; }
    int i = (off * 256 + threadIdx.x) * 4;
    float4 f = *(const float4*)(src + i);
    ushort4 o;
    o.x = f2bf(f.x); o.y = f2bf(f.y); o.z = f2bf(f.z); o.w = f2bf(f.w);
    *(ushort4*)(dst + i) = o;
}

// ---------------------------------------------------------------------------
// LayerNorm: fp32 in, bf16 out. One wave per 768-elem row, float4 loads.
// ---------------------------------------------------------------------------
__global__ __launch_bounds__(256) void ln_kernel(
    const float* __restrict__ x, const float* __restrict__ w,
    const float* __restrict__ b, unsigned short* __restrict__ y)
{
    int row  = blockIdx.x * 4 + (threadIdx.x >> 6);
    int lane = threadIdx.x & 63;
    const float4* xr = (const float4*)(x + (size_t)row * CDIM);
    float4 v[3];
    float s = 0.f, sq = 0.f;
#pragma unroll
    for (int i = 0; i < 3; i++) {
        float4 f = xr[lane + i * 64];
        v[i] = f;
        s  += (f.x + f.y) + (f.z + f.w);
        sq += (f.x * f.x + f.y * f.y) + (f.z * f.z + f.w * f.w);
    }
#pragma unroll
    for (int o = 32; o > 0; o >>= 1) {
        s  += __shfl_xor(s,  o, 64);
        sq += __shfl_xor(sq, o, 64);
    }
    float mean = s * (1.f / CDIM);
    float var  = sq * (1.f / CDIM) - mean * mean;
    float rstd = rsqrtf(var + 1e-5f);
    const float4* w4 = (const float4*)w;
    const float4* b4 = (const float4*)b;
    ushort4* y4 = (ushort4*)(y + (size_t)row * CDIM);
#pragma unroll
    for (int i = 0; i < 3; i++) {
        int c = lane + i * 64;
        float4 wf = w4[c], bf_ = b4[c];
        ushort4 o;
        o.x = f2bf((v[i].x - mean) * rstd * wf.x + bf_.x);
        o.y = f2bf((v[i].y - mean) * rstd * wf.y + bf_.y);
        o.z = f2bf((v[i].z - mean) * rstd * wf.z + bf_.z);
        o.w = f2bf((v[i].w - mean) * rstd * wf.w + bf_.w);
        y4[c] = o;
    }
}

// ---------------------------------------------------------------------------
// GEMM: C[M,N] = act(A[M,K] @ W[N,K]^T + bias + residual), BK=64.
// TM = block M-tile (128 or 64); BN fixed 128. 4 waves:
//   TM=128: 2x2 waves, each 64x64 (MT=4);  TM=64: 2x2 waves, each 32x64 (MT=2).
// Staging via global_load_lds width-16: lane -> row lane>>3, col (lane&7)*8.
// cols < scol scaled by `scale` before store (Q pre-scaling).
// ---------------------------------------------------------------------------
#define BK 64

template<int ACT, int OUT32, int TM>
__global__ __launch_bounds__(256) void gemm_bt(
    const unsigned short* __restrict__ A, const unsigned short* __restrict__ W,
    const float* __restrict__ bias, const float* __restrict__ res,
    void* __restrict__ Cv, int M, int N, int K, int scol, float scale)
{
    constexpr int MT   = TM / 32;      // frags in M per wave (4 or 2)
    constexpr int ISSA = TM / 32;      // A gload issues per wave
    __shared__ __align__(16) unsigned short As[TM * BK];    // 16 or 8 KB
    __shared__ __align__(16) unsigned short Bs[128 * BK];   // 16 KB
    int tid  = threadIdx.x;
    int wave = tid >> 6, lane = tid & 63;
    int wr = wave >> 1, wc = wave & 1;
    int quad = lane >> 4, l15 = lane & 15;
    int m0 = blockIdx.y * TM, n0 = blockIdx.x * 128;

    const unsigned short* Ag = A + (size_t)(m0 + wave * (TM / 4) + (lane >> 3)) * K + (lane & 7) * 8;
    const unsigned short* Wg = W + (size_t)(n0 + wave * 32 + (lane >> 3)) * K + (lane & 7) * 8;
    unsigned short* AsW = As + wave * (TM / 4) * BK;
    unsigned short* BsW = Bs + wave * 32 * BK;

    floatx4 acc[MT][4];
    floatx4 fz = {0.f, 0.f, 0.f, 0.f};
#pragma unroll
    for (int i = 0; i < MT; i++)
#pragma unroll
        for (int j = 0; j < 4; j++) acc[i][j] = fz;

    for (int k0 = 0; k0 < K; k0 += BK) {
        __syncthreads();   // prior readers done before overwrite
#pragma unroll
        for (int j = 0; j < ISSA; j++)
            gload16(Ag + (size_t)(8 * j) * K + k0, AsW + j * 512);
#pragma unroll
        for (int j = 0; j < 4; j++)
            gload16(Wg + (size_t)(8 * j) * K + k0, BsW + j * 512);
        __syncthreads();   // drain: DMA visible

#pragma unroll
        for (int s = 0; s < 2; s++) {
            short8 af[MT], bfg[4];
#pragma unroll
            for (int mt = 0; mt < MT; mt++)
                af[mt] = *(const short8*)(As + (wr * (TM / 2) + mt * 16 + l15) * BK + s * 32 + quad * 8);
#pragma unroll
            for (int nt = 0; nt < 4; nt++)
                bfg[nt] = *(const short8*)(Bs + (wc * 64 + nt * 16 + l15) * BK + s * 32 + quad * 8);
#pragma unroll
            for (int mt = 0; mt < MT; mt++)
#pragma unroll
                for (int nt = 0; nt < 4; nt++)
                    acc[mt][nt] = __builtin_amdgcn_mfma_f32_16x16x32_bf16(
                        af[mt], bfg[nt], acc[mt][nt], 0, 0, 0);
        }
    }

#pragma unroll
    for (int mt = 0; mt < MT; mt++) {
#pragma unroll
        for (int nt = 0; nt < 4; nt++) {
            int col = n0 + wc * 64 + nt * 16 + l15;
            float bv = bias ? bias[col] : 0.f;
            float cs = (col < scol) ? scale : 1.f;
#pragma unroll
            for (int r = 0; r < 4; r++) {
                int row = m0 + wr * (TM / 2) + mt * 16 + quad * 4 + r;
                size_t idx = (size_t)row * N + col;
                float v = acc[mt][nt][r] + bv;
                if (res) v += res[idx];
                if (ACT == 1) v = gelu_f(v);
                v *= cs;
                if (OUT32) ((float*)Cv)[idx] = v;
                else       ((unsigned short*)Cv)[idx] = f2bf(v);
            }
        }
    }
}

// ---------------------------------------------------------------------------
// Flash attention, transposed-S form (unchanged from R4).
// ---------------------------------------------------------------------------
__global__ __launch_bounds__(256) void attn_kernel(
    const unsigned short* __restrict__ qkv, unsigned short* __restrict__ out)
{
    __shared__ __align__(16) unsigned short Ks[2][64 * 72];
    __shared__ __align__(16) unsigned short Vt[2][64 * 72];   // Vt[d][key]
    __shared__ __align__(16) unsigned short Ps[4][16 * 72];   // [qrow][key]

    int tid  = threadIdx.x;
    int wave = tid >> 6, lane = tid & 63;
    int quad = lane >> 4, l15 = lane & 15;
    int bh = blockIdx.y;
    int b  = bh / NH, h = bh % NH;
    size_t base = (size_t)b * SEQ * 2304 + h * 64;
    int qbase = blockIdx.x * 64 + wave * 16;

    short8 bq[2];
#pragma unroll
    for (int kk = 0; kk < 2; kk++)
        bq[kk] = *(const short8*)(qkv + base + (size_t)(qbase + l15) * 2304 + kk * 32 + quad * 8);

    floatx4 o[4];
    floatx4 fz = {0.f, 0.f, 0.f, 0.f};
#pragma unroll
    for (int dg = 0; dg < 4; dg++) o[dg] = fz;
    float m = -3e38f, lsum = 0.f;

    const unsigned short* kptr = qkv + base + 768;
    const unsigned short* vptr = qkv + base + 1536;

    int skey = tid >> 2;
    int sd   = (tid & 3) * 16;
    int vj   = tid & 31;
    int vd8  = wave * 16 + ((tid >> 5) & 1) * 8;

    uint4 k0v = *(const uint4*)(kptr + (size_t)skey * 2304 + sd);
    uint4 k1v = *(const uint4*)(kptr + (size_t)skey * 2304 + sd + 8);
    uint4 v0v = *(const uint4*)(vptr + (size_t)(2 * vj)     * 2304 + vd8);
    uint4 v1v = *(const uint4*)(vptr + (size_t)(2 * vj + 1) * 2304 + vd8);

    for (int t = 0; t < SEQ / 64; t++) {
        int cur = t & 1;
        unsigned short* K_ = Ks[cur];
        unsigned short* V_ = Vt[cur];
        *(uint4*)(K_ + skey * 72 + sd)     = k0v;
        *(uint4*)(K_ + skey * 72 + sd + 8) = k1v;
        union { uint4 q; unsigned short u[8]; } u0, u1;
        u0.q = v0v; u1.q = v1v;
#pragma unroll
        for (int i = 0; i < 8; i++) {
            unsigned int w = (unsigned int)u0.u[i] | ((unsigned int)u1.u[i] << 16);
            *(unsigned int*)(V_ + (vd8 + i) * 72 + 2 * vj) = w;
        }
        __syncthreads();

        if (t + 1 < SEQ / 64) {
            int kt = (t + 1) * 64;
            k0v = *(const uint4*)(kptr + (size_t)(kt + skey) * 2304 + sd);
            k1v = *(const uint4*)(kptr + (size_t)(kt + skey) * 2304 + sd + 8);
            v0v = *(const uint4*)(vptr + (size_t)(kt + 2 * vj)     * 2304 + vd8);
            v1v = *(const uint4*)(vptr + (size_t)(kt + 2 * vj + 1) * 2304 + vd8);
        }

        floatx4 st[4];
#pragma unroll
        for (int ts = 0; ts < 4; ts++) {
            floatx4 s = fz;
#pragma unroll
            for (int kk = 0; kk < 2; kk++) {
                short8 ak = *(const short8*)(K_ + (ts * 16 + l15) * 72 + kk * 32 + quad * 8);
                s = __builtin_amdgcn_mfma_f32_16x16x32_bf16(ak, bq[kk], s, 0, 0, 0);
            }
            st[ts] = s;
        }

        float tmax = st[0][0];
#pragma unroll
        for (int ts = 0; ts < 4; ts++)
#pragma unroll
            for (int r = 0; r < 4; r++) tmax = fmaxf(tmax, st[ts][r]);
        tmax = fmaxf(tmax, __shfl_xor(tmax, 16, 64));
        tmax = fmaxf(tmax, __shfl_xor(tmax, 32, 64));
        if (tmax > m) {
            float alpha = fast_exp2(m - tmax);
            m = tmax;
            lsum *= alpha;
#pragma unroll
            for (int dg = 0; dg < 4; dg++)
#pragma unroll
                for (int r = 0; r < 4; r++) o[dg][r] *= alpha;
        }
        float p[4][4];
        float ps = 0.f;
#pragma unroll
        for (int ts = 0; ts < 4; ts++)
#pragma unroll
            for (int r = 0; r < 4; r++) {
                p[ts][r] = fast_exp2(st[ts][r] - m);
                ps += p[ts][r];
            }
        lsum += ps;
#pragma unroll
        for (int ts = 0; ts < 4; ts++) {
            unsigned int w01 = __builtin_amdgcn_perm(fbits(p[ts][1]), fbits(p[ts][0]), 0x07060302);
            unsigned int w23 = __builtin_amdgcn_perm(fbits(p[ts][3]), fbits(p[ts][2]), 0x07060302);
            uint2 wv; wv.x = w01; wv.y = w23;
            *(uint2*)(Ps[wave] + l15 * 72 + ts * 16 + quad * 4) = wv;
        }

#pragma unroll
        for (int half = 0; half < 2; half++) {
            short8 bp = *(const short8*)(Ps[wave] + l15 * 72 + half * 32 + quad * 8);
#pragma unroll
            for (int dg = 0; dg < 4; dg++) {
                short8 av = *(const short8*)(V_ + (dg * 16 + l15) * 72 + half * 32 + quad * 8);
                o[dg] = __builtin_amdgcn_mfma_f32_16x16x32_bf16(av, bp, o[dg], 0, 0, 0);
            }
        }
    }

    lsum += __shfl_xor(lsum, 16, 64);
    lsum += __shfl_xor(lsum, 32, 64);
    float inv = 1.f / lsum;
    size_t orow = ((size_t)b * SEQ + qbase + l15) * CDIM + h * 64;
#pragma unroll
    for (int dg = 0; dg < 4; dg++) {
        unsigned int u0 = (unsigned int)f2bf(o[dg][0] * inv) | ((unsigned int)f2bf(o[dg][1] * inv) << 16);
        unsigned int u1 = (unsigned int)f2bf(o[dg][2] * inv) | ((unsigned int)f2bf(o[dg][3] * inv) << 16);
        uint2 wv; wv.x = u0; wv.y = u1;
        *(uint2*)((unsigned short*)out + orow + dg * 16 + quad * 4) = wv;
    }
}

// ---------------------------------------------------------------------------
extern "C" void kernel_launch(void* const* d_in, const int* in_sizes, int n_in,
                              void* d_out, int out_size, void* d_ws, size_t ws_size,
                              hipStream_t stream)
{
    const float* x      = (const float*)d_in[0];
    const float* qkv_w  = (const float*)d_in[1];
    const float* proj_w = (const float*)d_in[2];
    const float* proj_b = (const float*)d_in[3];
    const float* n1w    = (const float*)d_in[4];
    const float* n1b    = (const float*)d_in[5];
    const float* n2w    = (const float*)d_in[6];
    const float* n2b    = (const float*)d_in[7];
    const float* fc1w   = (const float*)d_in[8];
    const float* fc1b   = (const float*)d_in[9];
    const float* fc2w   = (const float*)d_in[10];
    const float* fc2b   = (const float*)d_in[11];
    float* out = (float*)d_out;   // doubles as x2 (post-attn residual, fp32)

    unsigned short* ws = (unsigned short*)d_ws;
    unsigned short* wq = ws;                    // 1,769,472
    unsigned short* wp = wq + 1769472;          //   589,824
    unsigned short* w1 = wp + 589824;           // 2,359,296
    unsigned short* w2 = w1 + 2359296;          // 2,359,296
    unsigned short* h    = w2 + 2359296;        // 6,291,456
    unsigned short* qkv  = h + 6291456;         // 18,874,368
    unsigned short* attn = qkv + 18874368;      // 6,291,456
    unsigned short* a    = qkv;                 // fc1 out reuses qkv+attn

    dim3 blk(256);
    cvt_all_kernel<<<6912, blk, 0, stream>>>(qkv_w, proj_w, fc1w, fc2w, wq, wp, w1, w2);

    ln_kernel<<<NTOK / 4, blk, 0, stream>>>(x, n1w, n1b, h);
    gemm_bt<0, 0, 128><<<dim3(2304 / 128, NTOK / 128), blk, 0, stream>>>(
        h, wq, nullptr, nullptr, qkv, NTOK, 2304, 768, 768, KS2);   // scale Q cols
    attn_kernel<<<dim3(SEQ / 64, NBAT * NH), blk, 0, stream>>>(qkv, attn);
    gemm_bt<0, 1, 64><<<dim3(768 / 128, NTOK / 64), blk, 0, stream>>>(
        attn, wp, proj_b, x, out, NTOK, 768, 768, 0, 1.f);
    ln_kernel<<<NTOK / 4, blk, 0, stream>>>(out, n2w, n2b, h);
    gemm_bt<1, 0, 128><<<dim3(3072 / 128, NTOK / 128), blk, 0, stream>>>(
        h, w1, fc1b, nullptr, a, NTOK, 3072, 768, 0, 1.f);
    gemm_bt<0, 1, 64><<<dim3(768 / 128, NTOK / 64), blk, 0, stream>>>(
        a, w2, fc2b, out, out, NTOK, 768, 3072, 0, 1.f);
}

// Round 6
// 406.997 us; speedup vs baseline: 1.4245x; 1.1436x over previous
//
#include <hip/hip_runtime.h>
#include <hip/hip_bf16.h>

#define SEQ   2048
#define NBAT  4
#define NH    12
#define HD    64
#define CDIM  768
#define HID   3072
#define NTOK  (SEQ*NBAT)   // 8192 rows

#define KS2 0.1803368801111244f   // 0.125 * log2(e), folded into Q

typedef __attribute__((ext_vector_type(8))) short short8;   // 8 bf16 (4 VGPRs)
typedef __attribute__((ext_vector_type(4))) float floatx4;  // MFMA C/D

__device__ __forceinline__ float bf2f(unsigned short u) {
    union { unsigned int i; float f; } v; v.i = ((unsigned int)u) << 16; return v.f;
}
__device__ __forceinline__ unsigned short f2bf(float f) {
    union { float f; unsigned int i; } v; v.f = f;
    unsigned int i = v.i;
    return (unsigned short)((i + 0x7FFFu + ((i >> 16) & 1u)) >> 16);  // RNE
}
__device__ __forceinline__ unsigned int fbits(float f) {
    union { float f; unsigned int i; } v; v.f = f; return v.i;
}
__device__ __forceinline__ float fast_exp2(float x) {   // native v_exp_f32
#if __has_builtin(__builtin_amdgcn_exp2f)
    return __builtin_amdgcn_exp2f(x);
#else
    return __expf(x * 0.69314718055994531f);
#endif
}
__device__ __forceinline__ float fast_rcp(float x) {
#if __has_builtin(__builtin_amdgcn_rcpf)
    return __builtin_amdgcn_rcpf(x);
#else
    return 1.f / x;
#endif
}
// tanh-form GELU with native ops only
__device__ __forceinline__ float gelu_f(float v) {
    float u = 0.7978845608028654f * v * (1.f + 0.044715f * v * v);
    float e = fast_exp2(u * 2.885390081777927f);      // e^(2u)
    float th = 1.f - 2.f * fast_rcp(e + 1.f);         // tanh(u)
    return 0.5f * v * (1.f + th);
}
// async global->LDS, 16B/lane; LDS dest = wave-uniform base + lane*16B
__device__ __forceinline__ void gload16(const unsigned short* g, unsigned short* l) {
    __builtin_amdgcn_global_load_lds(
        (const __attribute__((address_space(1))) unsigned int*)g,
        (__attribute__((address_space(3))) unsigned int*)l, 16, 0, 0);
}

// ---------------------------------------------------------------------------
// fp32 -> bf16 conversion of all 4 weight matrices in ONE launch.
// ---------------------------------------------------------------------------
__global__ __launch_bounds__(256) void cvt_all_kernel(
    const float* __restrict__ s0, const float* __restrict__ s1,
    const float* __restrict__ s2, const float* __restrict__ s3,
    unsigned short* __restrict__ d0, unsigned short* __restrict__ d1,
    unsigned short* __restrict__ d2, unsigned short* __restrict__ d3)
{
    int blk = blockIdx.x;
    const float* src; unsigned short* dst; int off;
    if (blk < 1728)      { src = s0; dst = d0; off = blk; }
    else if (blk < 2304) { src = s1; dst = d1; off = blk - 1728; }
    else if (blk < 4608) { src = s2; dst = d2; off = blk - 2304; }
    else                 { src = s3; dst = d3; off = blk - 4608; }
    int i = (off * 256 + threadIdx.x) * 4;
    float4 f = *(const float4*)(src + i);
    ushort4 o;
    o.x = f2bf(f.x); o.y = f2bf(f.y); o.z = f2bf(f.z); o.w = f2bf(f.w);
    *(ushort4*)(dst + i) = o;
}

// ---------------------------------------------------------------------------
// LayerNorm: fp32 in, bf16 out. One wave per 768-elem row, float4 loads.
// ---------------------------------------------------------------------------
__global__ __launch_bounds__(256) void ln_kernel(
    const float* __restrict__ x, const float* __restrict__ w,
    const float* __restrict__ b, unsigned short* __restrict__ y)
{
    int row  = blockIdx.x * 4 + (threadIdx.x >> 6);
    int lane = threadIdx.x & 63;
    const float4* xr = (const float4*)(x + (size_t)row * CDIM);
    float4 v[3];
    float s = 0.f, sq = 0.f;
#pragma unroll
    for (int i = 0; i < 3; i++) {
        float4 f = xr[lane + i * 64];
        v[i] = f;
        s  += (f.x + f.y) + (f.z + f.w);
        sq += (f.x * f.x + f.y * f.y) + (f.z * f.z + f.w * f.w);
    }
#pragma unroll
    for (int o = 32; o > 0; o >>= 1) {
        s  += __shfl_xor(s,  o, 64);
        sq += __shfl_xor(sq, o, 64);
    }
    float mean = s * (1.f / CDIM);
    float var  = sq * (1.f / CDIM) - mean * mean;
    float rstd = rsqrtf(var + 1e-5f);
    const float4* w4 = (const float4*)w;
    const float4* b4 = (const float4*)b;
    ushort4* y4 = (ushort4*)(y + (size_t)row * CDIM);
#pragma unroll
    for (int i = 0; i < 3; i++) {
        int c = lane + i * 64;
        float4 wf = w4[c], bf_ = b4[c];
        ushort4 o;
        o.x = f2bf((v[i].x - mean) * rstd * wf.x + bf_.x);
        o.y = f2bf((v[i].y - mean) * rstd * wf.y + bf_.y);
        o.z = f2bf((v[i].z - mean) * rstd * wf.z + bf_.z);
        o.w = f2bf((v[i].w - mean) * rstd * wf.w + bf_.w);
        y4[c] = o;
    }
}

// ---------------------------------------------------------------------------
// GEMM: C[M,N] = act(A[M,K] @ W[N,K]^T + bias + residual), BK=64.
// Grid: x = M-tiles (FASTEST -> consecutive blocks share the W-tile, L2 reuse),
//       y = N-tiles (128 wide).
// XOR-swizzled LDS staging: global kchunk c of row r lives at LDS slot
// c ^ (r&7)  -> ds_read_b128 frag reads are 2-way (free) instead of 16-way.
// cols < scol scaled by `scale` before store (Q pre-scaling).
// ---------------------------------------------------------------------------
#define BK 64

template<int ACT, int OUT32, int TM>
__global__ __launch_bounds__(256) void gemm_bt(
    const unsigned short* __restrict__ A, const unsigned short* __restrict__ W,
    const float* __restrict__ bias, const float* __restrict__ res,
    void* __restrict__ Cv, int M, int N, int K, int scol, float scale)
{
    constexpr int MT   = TM / 32;      // M frags per wave (4 or 2)
    constexpr int ISSA = TM / 32;      // A gload issues per wave
    __shared__ __align__(16) unsigned short As[TM * BK];
    __shared__ __align__(16) unsigned short Bs[128 * BK];
    int tid  = threadIdx.x;
    int wave = tid >> 6, lane = tid & 63;
    int wr = wave >> 1, wc = wave & 1;
    int quad = lane >> 4, l15 = lane & 15;
    int m0 = blockIdx.x * TM, n0 = blockIdx.y * 128;

    int r8 = lane >> 3;                        // row-in-8 for staging
    int kc = (lane & 7) ^ r8;                  // swizzled source k-chunk
    const unsigned short* Ag = A + (size_t)(m0 + wave * (TM / 4) + r8) * K + kc * 8;
    const unsigned short* Wg = W + (size_t)(n0 + wave * 32 + r8) * K + kc * 8;
    unsigned short* AsW = As + wave * (TM / 4) * BK;
    unsigned short* BsW = Bs + wave * 32 * BK;

    floatx4 acc[MT][4];
    floatx4 fz = {0.f, 0.f, 0.f, 0.f};
#pragma unroll
    for (int i = 0; i < MT; i++)
#pragma unroll
        for (int j = 0; j < 4; j++) acc[i][j] = fz;

    int sw = l15 & 7;                          // read-side swizzle key
    for (int k0 = 0; k0 < K; k0 += BK) {
        __syncthreads();   // prior readers done before overwrite
#pragma unroll
        for (int j = 0; j < ISSA; j++)
            gload16(Ag + (size_t)(8 * j) * K + k0, AsW + j * 512);
#pragma unroll
        for (int j = 0; j < 4; j++)
            gload16(Wg + (size_t)(8 * j) * K + k0, BsW + j * 512);
        __syncthreads();   // drain: DMA visible

#pragma unroll
        for (int s = 0; s < 2; s++) {
            short8 af[MT], bfg[4];
            int ko = ((s * 4 + quad) ^ sw) * 8;   // swizzled k-offset
#pragma unroll
            for (int mt = 0; mt < MT; mt++)
                af[mt] = *(const short8*)(As + (wr * (TM / 2) + mt * 16 + l15) * BK + ko);
#pragma unroll
            for (int nt = 0; nt < 4; nt++)
                bfg[nt] = *(const short8*)(Bs + (wc * 64 + nt * 16 + l15) * BK + ko);
#pragma unroll
            for (int mt = 0; mt < MT; mt++)
#pragma unroll
                for (int nt = 0; nt < 4; nt++)
                    acc[mt][nt] = __builtin_amdgcn_mfma_f32_16x16x32_bf16(
                        af[mt], bfg[nt], acc[mt][nt], 0, 0, 0);
        }
    }

#pragma unroll
    for (int mt = 0; mt < MT; mt++) {
#pragma unroll
        for (int nt = 0; nt < 4; nt++) {
            int col = n0 + wc * 64 + nt * 16 + l15;
            float bv = bias ? bias[col] : 0.f;
            float cs = (col < scol) ? scale : 1.f;
#pragma unroll
            for (int r = 0; r < 4; r++) {
                int row = m0 + wr * (TM / 2) + mt * 16 + quad * 4 + r;
                size_t idx = (size_t)row * N + col;
                float v = acc[mt][nt][r] + bv;
                if (res) v += res[idx];
                if (ACT == 1) v = gelu_f(v);
                v *= cs;
                if (OUT32) ((float*)Cv)[idx] = v;
                else       ((unsigned short*)Cv)[idx] = f2bf(v);
            }
        }
    }
}

// ---------------------------------------------------------------------------
// Flash attention, transposed-S, 128 q-rows/block (4 waves x 32 q).
// Each wave: two 16-row q-halves sharing one Ps buffer (wave-private,
// same-wave DS ordering makes reuse safe). K/V staging amortized over 2x q.
// ---------------------------------------------------------------------------
__global__ __launch_bounds__(256) void attn_kernel(
    const unsigned short* __restrict__ qkv, unsigned short* __restrict__ out)
{
    __shared__ __align__(16) unsigned short Ks[2][64 * 72];
    __shared__ __align__(16) unsigned short Vt[2][64 * 72];   // Vt[d][key]
    __shared__ __align__(16) unsigned short Ps[4][16 * 72];   // [qrow16][key]

    int tid  = threadIdx.x;
    int wave = tid >> 6, lane = tid & 63;
    int quad = lane >> 4, l15 = lane & 15;
    int bh = blockIdx.y;
    int b  = bh / NH, h = bh % NH;
    size_t base = (size_t)b * SEQ * 2304 + h * 64;
    int qbase = blockIdx.x * 128 + wave * 32;

    // Q B-frags for both 16-row halves
    short8 bq[2][2];
#pragma unroll
    for (int qh = 0; qh < 2; qh++)
#pragma unroll
        for (int kk = 0; kk < 2; kk++)
            bq[qh][kk] = *(const short8*)(qkv + base +
                (size_t)(qbase + qh * 16 + l15) * 2304 + kk * 32 + quad * 8);

    floatx4 o[2][4];
    floatx4 fz = {0.f, 0.f, 0.f, 0.f};
#pragma unroll
    for (int qh = 0; qh < 2; qh++)
#pragma unroll
        for (int dg = 0; dg < 4; dg++) o[qh][dg] = fz;
    float m2[2]  = {-3e38f, -3e38f};
    float ls[2]  = {0.f, 0.f};

    const unsigned short* kptr = qkv + base + 768;
    const unsigned short* vptr = qkv + base + 1536;

    int skey = tid >> 2;
    int sd   = (tid & 3) * 16;
    int vj   = tid & 31;
    int vd8  = wave * 16 + ((tid >> 5) & 1) * 8;

    uint4 k0v = *(const uint4*)(kptr + (size_t)skey * 2304 + sd);
    uint4 k1v = *(const uint4*)(kptr + (size_t)skey * 2304 + sd + 8);
    uint4 v0v = *(const uint4*)(vptr + (size_t)(2 * vj)     * 2304 + vd8);
    uint4 v1v = *(const uint4*)(vptr + (size_t)(2 * vj + 1) * 2304 + vd8);

    for (int t = 0; t < SEQ / 64; t++) {
        int cur = t & 1;
        unsigned short* K_ = Ks[cur];
        unsigned short* V_ = Vt[cur];
        *(uint4*)(K_ + skey * 72 + sd)     = k0v;
        *(uint4*)(K_ + skey * 72 + sd + 8) = k1v;
        union { uint4 q; unsigned short u[8]; } u0, u1;
        u0.q = v0v; u1.q = v1v;
#pragma unroll
        for (int i = 0; i < 8; i++) {
            unsigned int w = (unsigned int)u0.u[i] | ((unsigned int)u1.u[i] << 16);
            *(unsigned int*)(V_ + (vd8 + i) * 72 + 2 * vj) = w;
        }
        __syncthreads();

        if (t + 1 < SEQ / 64) {
            int kt = (t + 1) * 64;
            k0v = *(const uint4*)(kptr + (size_t)(kt + skey) * 2304 + sd);
            k1v = *(const uint4*)(kptr + (size_t)(kt + skey) * 2304 + sd + 8);
            v0v = *(const uint4*)(vptr + (size_t)(kt + 2 * vj)     * 2304 + vd8);
            v1v = *(const uint4*)(vptr + (size_t)(kt + 2 * vj + 1) * 2304 + vd8);
        }

#pragma unroll
        for (int qh = 0; qh < 2; qh++) {
            // S^T: st[ts][r] = score(key = ts*16 + quad*4 + r, qrow = l15)
            floatx4 st[4];
#pragma unroll
            for (int ts = 0; ts < 4; ts++) {
                floatx4 s = fz;
#pragma unroll
                for (int kk = 0; kk < 2; kk++) {
                    short8 ak = *(const short8*)(K_ + (ts * 16 + l15) * 72 + kk * 32 + quad * 8);
                    s = __builtin_amdgcn_mfma_f32_16x16x32_bf16(ak, bq[qh][kk], s, 0, 0, 0);
                }
                st[ts] = s;
            }

            float tmax = st[0][0];
#pragma unroll
            for (int ts = 0; ts < 4; ts++)
#pragma unroll
                for (int r = 0; r < 4; r++) tmax = fmaxf(tmax, st[ts][r]);
            tmax = fmaxf(tmax, __shfl_xor(tmax, 16, 64));
            tmax = fmaxf(tmax, __shfl_xor(tmax, 32, 64));
            if (tmax > m2[qh]) {
                float alpha = fast_exp2(m2[qh] - tmax);
                m2[qh] = tmax;
                ls[qh] *= alpha;
#pragma unroll
                for (int dg = 0; dg < 4; dg++)
#pragma unroll
                    for (int r = 0; r < 4; r++) o[qh][dg][r] *= alpha;
            }
            float p[4][4];
            float psum = 0.f;
            float mm = m2[qh];
#pragma unroll
            for (int ts = 0; ts < 4; ts++)
#pragma unroll
                for (int r = 0; r < 4; r++) {
                    p[ts][r] = fast_exp2(st[ts][r] - mm);
                    psum += p[ts][r];
                }
            ls[qh] += psum;
#pragma unroll
            for (int ts = 0; ts < 4; ts++) {
                unsigned int w01 = __builtin_amdgcn_perm(fbits(p[ts][1]), fbits(p[ts][0]), 0x07060302);
                unsigned int w23 = __builtin_amdgcn_perm(fbits(p[ts][3]), fbits(p[ts][2]), 0x07060302);
                uint2 wv; wv.x = w01; wv.y = w23;
                *(uint2*)(Ps[wave] + l15 * 72 + ts * 16 + quad * 4) = wv;
            }

            // O^T += V^T P  (same-wave DS ordering: Ps reuse across qh is safe)
#pragma unroll
            for (int hk = 0; hk < 2; hk++) {
                short8 bp = *(const short8*)(Ps[wave] + l15 * 72 + hk * 32 + quad * 8);
#pragma unroll
                for (int dg = 0; dg < 4; dg++) {
                    short8 av = *(const short8*)(V_ + (dg * 16 + l15) * 72 + hk * 32 + quad * 8);
                    o[qh][dg] = __builtin_amdgcn_mfma_f32_16x16x32_bf16(av, bp, o[qh][dg], 0, 0, 0);
                }
            }
        }
    }

#pragma unroll
    for (int qh = 0; qh < 2; qh++) {
        float l = ls[qh];
        l += __shfl_xor(l, 16, 64);
        l += __shfl_xor(l, 32, 64);
        float inv = 1.f / l;
        size_t orow = ((size_t)b * SEQ + qbase + qh * 16 + l15) * CDIM + h * 64;
#pragma unroll
        for (int dg = 0; dg < 4; dg++) {
            unsigned int u0 = (unsigned int)f2bf(o[qh][dg][0] * inv) | ((unsigned int)f2bf(o[qh][dg][1] * inv) << 16);
            unsigned int u1 = (unsigned int)f2bf(o[qh][dg][2] * inv) | ((unsigned int)f2bf(o[qh][dg][3] * inv) << 16);
            uint2 wv; wv.x = u0; wv.y = u1;
            *(uint2*)((unsigned short*)out + orow + dg * 16 + quad * 4) = wv;
        }
    }
}

// ---------------------------------------------------------------------------
extern "C" void kernel_launch(void* const* d_in, const int* in_sizes, int n_in,
                              void* d_out, int out_size, void* d_ws, size_t ws_size,
                              hipStream_t stream)
{
    const float* x      = (const float*)d_in[0];
    const float* qkv_w  = (const float*)d_in[1];
    const float* proj_w = (const float*)d_in[2];
    const float* proj_b = (const float*)d_in[3];
    const float* n1w    = (const float*)d_in[4];
    const float* n1b    = (const float*)d_in[5];
    const float* n2w    = (const float*)d_in[6];
    const float* n2b    = (const float*)d_in[7];
    const float* fc1w   = (const float*)d_in[8];
    const float* fc1b   = (const float*)d_in[9];
    const float* fc2w   = (const float*)d_in[10];
    const float* fc2b   = (const float*)d_in[11];
    float* out = (float*)d_out;   // doubles as x2 (post-attn residual, fp32)

    unsigned short* ws = (unsigned short*)d_ws;
    unsigned short* wq = ws;                    // 1,769,472
    unsigned short* wp = wq + 1769472;          //   589,824
    unsigned short* w1 = wp + 589824;           // 2,359,296
    unsigned short* w2 = w1 + 2359296;          // 2,359,296
    unsigned short* h    = w2 + 2359296;        // 6,291,456
    unsigned short* qkv  = h + 6291456;         // 18,874,368
    unsigned short* attn = qkv + 18874368;      // 6,291,456
    unsigned short* a    = qkv;                 // fc1 out reuses qkv+attn

    dim3 blk(256);
    cvt_all_kernel<<<6912, blk, 0, stream>>>(qkv_w, proj_w, fc1w, fc2w, wq, wp, w1, w2);

    ln_kernel<<<NTOK / 4, blk, 0, stream>>>(x, n1w, n1b, h);
    gemm_bt<0, 0, 128><<<dim3(NTOK / 128, 2304 / 128), blk, 0, stream>>>(
        h, wq, nullptr, nullptr, qkv, NTOK, 2304, 768, 768, KS2);   // scale Q cols
    attn_kernel<<<dim3(SEQ / 128, NBAT * NH), blk, 0, stream>>>(qkv, attn);
    gemm_bt<0, 1, 64><<<dim3(NTOK / 64, 768 / 128), blk, 0, stream>>>(
        attn, wp, proj_b, x, out, NTOK, 768, 768, 0, 1.f);
    ln_kernel<<<NTOK / 4, blk, 0, stream>>>(out, n2w, n2b, h);
    gemm_bt<1, 0, 128><<<dim3(NTOK / 128, 3072 / 128), blk, 0, stream>>>(
        h, w1, fc1b, nullptr, a, NTOK, 3072, 768, 0, 1.f);
    gemm_bt<0, 1, 64><<<dim3(NTOK / 64, 768 / 128), blk, 0, stream>>>(
        a, w2, fc2b, out, out, NTOK, 768, 3072, 0, 1.f);
}

// Round 7
// 397.423 us; speedup vs baseline: 1.4588x; 1.0241x over previous
//
#include <hip/hip_runtime.h>
#include <hip/hip_bf16.h>

#define SEQ   2048
#define NBAT  4
#define NH    12
#define HD    64
#define CDIM  768
#define HID   3072
#define NTOK  (SEQ*NBAT)   // 8192 rows

#define KS2 0.1803368801111244f   // 0.125 * log2(e), folded into Q

typedef __attribute__((ext_vector_type(8))) short short8;   // 8 bf16 (4 VGPRs)
typedef __attribute__((ext_vector_type(4))) float floatx4;  // MFMA C/D

__device__ __forceinline__ float bf2f(unsigned short u) {
    union { unsigned int i; float f; } v; v.i = ((unsigned int)u) << 16; return v.f;
}
__device__ __forceinline__ unsigned short f2bf(float f) {
    union { float f; unsigned int i; } v; v.f = f;
    unsigned int i = v.i;
    return (unsigned short)((i + 0x7FFFu + ((i >> 16) & 1u)) >> 16);  // RNE
}
__device__ __forceinline__ unsigned int fbits(float f) {
    union { float f; unsigned int i; } v; v.f = f; return v.i;
}
__device__ __forceinline__ float fast_exp2(float x) {   // native v_exp_f32
#if __has_builtin(__builtin_amdgcn_exp2f)
    return __builtin_amdgcn_exp2f(x);
#else
    return __expf(x * 0.69314718055994531f);
#endif
}
__device__ __forceinline__ float fast_rcp(float x) {
#if __has_builtin(__builtin_amdgcn_rcpf)
    return __builtin_amdgcn_rcpf(x);
#else
    return 1.f / x;
#endif
}
// tanh-form GELU with native ops only
__device__ __forceinline__ float gelu_f(float v) {
    float u = 0.7978845608028654f * v * (1.f + 0.044715f * v * v);
    float e = fast_exp2(u * 2.885390081777927f);      // e^(2u)
    float th = 1.f - 2.f * fast_rcp(e + 1.f);         // tanh(u)
    return 0.5f * v * (1.f + th);
}
// async global->LDS, 16B/lane; LDS dest = wave-uniform base + lane*16B
__device__ __forceinline__ void gload16(const unsigned short* g, unsigned short* l) {
    __builtin_amdgcn_global_load_lds(
        (const __attribute__((address_space(1))) unsigned int*)g,
        (__attribute__((address_space(3))) unsigned int*)l, 16, 0, 0);
}

// ---------------------------------------------------------------------------
// fp32 -> bf16 conversion of all 4 weight matrices in ONE launch.
// ---------------------------------------------------------------------------
__global__ __launch_bounds__(256) void cvt_all_kernel(
    const float* __restrict__ s0, const float* __restrict__ s1,
    const float* __restrict__ s2, const float* __restrict__ s3,
    unsigned short* __restrict__ d0, unsigned short* __restrict__ d1,
    unsigned short* __restrict__ d2, unsigned short* __restrict__ d3)
{
    int blk = blockIdx.x;
    const float* src; unsigned short* dst; int off;
    if (blk < 1728)      { src = s0; dst = d0; off = blk; }
    else if (blk < 2304) { src = s1; dst = d1; off = blk - 1728; }
    else if (blk < 4608) { src = s2; dst = d2; off = blk - 2304; }
    else                 { src = s3; dst = d3; off = blk - 4608; }
    int i = (off * 256 + threadIdx.x) * 4;
    float4 f = *(const float4*)(src + i);
    ushort4 o;
    o.x = f2bf(f.x); o.y = f2bf(f.y); o.z = f2bf(f.z); o.w = f2bf(f.w);
    *(ushort4*)(dst + i) = o;
}

// ---------------------------------------------------------------------------
// LayerNorm: fp32 in, bf16 out. One wave per 768-elem row, float4 loads.
// ---------------------------------------------------------------------------
__global__ __launch_bounds__(256) void ln_kernel(
    const float* __restrict__ x, const float* __restrict__ w,
    const float* __restrict__ b, unsigned short* __restrict__ y)
{
    int row  = blockIdx.x * 4 + (threadIdx.x >> 6);
    int lane = threadIdx.x & 63;
    const float4* xr = (const float4*)(x + (size_t)row * CDIM);
    float4 v[3];
    float s = 0.f, sq = 0.f;
#pragma unroll
    for (int i = 0; i < 3; i++) {
        float4 f = xr[lane + i * 64];
        v[i] = f;
        s  += (f.x + f.y) + (f.z + f.w);
        sq += (f.x * f.x + f.y * f.y) + (f.z * f.z + f.w * f.w);
    }
#pragma unroll
    for (int o = 32; o > 0; o >>= 1) {
        s  += __shfl_xor(s,  o, 64);
        sq += __shfl_xor(sq, o, 64);
    }
    float mean = s * (1.f / CDIM);
    float var  = sq * (1.f / CDIM) - mean * mean;
    float rstd = rsqrtf(var + 1e-5f);
    const float4* w4 = (const float4*)w;
    const float4* b4 = (const float4*)b;
    ushort4* y4 = (ushort4*)(y + (size_t)row * CDIM);
#pragma unroll
    for (int i = 0; i < 3; i++) {
        int c = lane + i * 64;
        float4 wf = w4[c], bf_ = b4[c];
        ushort4 o;
        o.x = f2bf((v[i].x - mean) * rstd * wf.x + bf_.x);
        o.y = f2bf((v[i].y - mean) * rstd * wf.y + bf_.y);
        o.z = f2bf((v[i].z - mean) * rstd * wf.z + bf_.z);
        o.w = f2bf((v[i].w - mean) * rstd * wf.w + bf_.w);
        y4[c] = o;
    }
}

// ---------------------------------------------------------------------------
// GEMM: C[M,N] = act(A[M,K] @ W[N,K]^T + bias + residual), BK=64.
// Grid: x = M-tiles (fastest -> consecutive blocks share W-tile, L2 reuse).
// XOR-swizzled LDS staging: kchunk c of row r at LDS slot c ^ (r&7).
// ---------------------------------------------------------------------------
#define BK 64

template<int ACT, int OUT32, int TM>
__global__ __launch_bounds__(256) void gemm_bt(
    const unsigned short* __restrict__ A, const unsigned short* __restrict__ W,
    const float* __restrict__ bias, const float* __restrict__ res,
    void* __restrict__ Cv, int M, int N, int K, int scol, float scale)
{
    constexpr int MT   = TM / 32;      // M frags per wave (4 or 2)
    constexpr int ISSA = TM / 32;      // A gload issues per wave
    __shared__ __align__(16) unsigned short As[TM * BK];
    __shared__ __align__(16) unsigned short Bs[128 * BK];
    int tid  = threadIdx.x;
    int wave = tid >> 6, lane = tid & 63;
    int wr = wave >> 1, wc = wave & 1;
    int quad = lane >> 4, l15 = lane & 15;
    int m0 = blockIdx.x * TM, n0 = blockIdx.y * 128;

    int r8 = lane >> 3;                        // row-in-8 for staging
    int kc = (lane & 7) ^ r8;                  // swizzled source k-chunk
    const unsigned short* Ag = A + (size_t)(m0 + wave * (TM / 4) + r8) * K + kc * 8;
    const unsigned short* Wg = W + (size_t)(n0 + wave * 32 + r8) * K + kc * 8;
    unsigned short* AsW = As + wave * (TM / 4) * BK;
    unsigned short* BsW = Bs + wave * 32 * BK;

    floatx4 acc[MT][4];
    floatx4 fz = {0.f, 0.f, 0.f, 0.f};
#pragma unroll
    for (int i = 0; i < MT; i++)
#pragma unroll
        for (int j = 0; j < 4; j++) acc[i][j] = fz;

    int sw = l15 & 7;                          // read-side swizzle key
    for (int k0 = 0; k0 < K; k0 += BK) {
        __syncthreads();   // prior readers done before overwrite
#pragma unroll
        for (int j = 0; j < ISSA; j++)
            gload16(Ag + (size_t)(8 * j) * K + k0, AsW + j * 512);
#pragma unroll
        for (int j = 0; j < 4; j++)
            gload16(Wg + (size_t)(8 * j) * K + k0, BsW + j * 512);
        __syncthreads();   // drain: DMA visible

#pragma unroll
        for (int s = 0; s < 2; s++) {
            short8 af[MT], bfg[4];
            int ko = ((s * 4 + quad) ^ sw) * 8;   // swizzled k-offset
#pragma unroll
            for (int mt = 0; mt < MT; mt++)
                af[mt] = *(const short8*)(As + (wr * (TM / 2) + mt * 16 + l15) * BK + ko);
#pragma unroll
            for (int nt = 0; nt < 4; nt++)
                bfg[nt] = *(const short8*)(Bs + (wc * 64 + nt * 16 + l15) * BK + ko);
#pragma unroll
            for (int mt = 0; mt < MT; mt++)
#pragma unroll
                for (int nt = 0; nt < 4; nt++)
                    acc[mt][nt] = __builtin_amdgcn_mfma_f32_16x16x32_bf16(
                        af[mt], bfg[nt], acc[mt][nt], 0, 0, 0);
        }
    }

#pragma unroll
    for (int mt = 0; mt < MT; mt++) {
#pragma unroll
        for (int nt = 0; nt < 4; nt++) {
            int col = n0 + wc * 64 + nt * 16 + l15;
            float bv = bias ? bias[col] : 0.f;
            float cs = (col < scol) ? scale : 1.f;
#pragma unroll
            for (int r = 0; r < 4; r++) {
                int row = m0 + wr * (TM / 2) + mt * 16 + quad * 4 + r;
                size_t idx = (size_t)row * N + col;
                float v = acc[mt][nt][r] + bv;
                if (res) v += res[idx];
                if (ACT == 1) v = gelu_f(v);
                v *= cs;
                if (OUT32) ((float*)Cv)[idx] = v;
                else       ((unsigned short*)Cv)[idx] = f2bf(v);
            }
        }
    }
}

// ---------------------------------------------------------------------------
// Flash attention, transposed-S, 64 q-rows/block, SINGLE-buffered K/V LDS
// (27.6 KB -> 5 blocks/CU = 20 waves) with early register prefetch:
//   issue loads(t+1) -> compute(t) -> barrier -> LDS write(t+1) -> barrier.
// Global latency hides under compute; vmcnt wait lands post-compute.
// ---------------------------------------------------------------------------
__global__ __launch_bounds__(256) void attn_kernel(
    const unsigned short* __restrict__ qkv, unsigned short* __restrict__ out)
{
    __shared__ __align__(16) unsigned short Ks[64 * 72];
    __shared__ __align__(16) unsigned short Vt[64 * 72];      // Vt[d][key]
    __shared__ __align__(16) unsigned short Ps[4][16 * 72];   // [qrow][key]

    int tid  = threadIdx.x;
    int wave = tid >> 6, lane = tid & 63;
    int quad = lane >> 4, l15 = lane & 15;
    int bh = blockIdx.y;
    int b  = bh / NH, h = bh % NH;
    size_t base = (size_t)b * SEQ * 2304 + h * 64;
    int qbase = blockIdx.x * 64 + wave * 16;

    short8 bq[2];
#pragma unroll
    for (int kk = 0; kk < 2; kk++)
        bq[kk] = *(const short8*)(qkv + base + (size_t)(qbase + l15) * 2304 + kk * 32 + quad * 8);

    floatx4 o[4];
    floatx4 fz = {0.f, 0.f, 0.f, 0.f};
#pragma unroll
    for (int dg = 0; dg < 4; dg++) o[dg] = fz;
    float m = -3e38f, lsum = 0.f;

    const unsigned short* kptr = qkv + base + 768;
    const unsigned short* vptr = qkv + base + 1536;

    int skey = tid >> 2;
    int sd   = (tid & 3) * 16;
    int vj   = tid & 31;
    int vd8  = wave * 16 + ((tid >> 5) & 1) * 8;

    // prologue: tile 0 regs -> LDS
    {
        uint4 k0v = *(const uint4*)(kptr + (size_t)skey * 2304 + sd);
        uint4 k1v = *(const uint4*)(kptr + (size_t)skey * 2304 + sd + 8);
        uint4 v0v = *(const uint4*)(vptr + (size_t)(2 * vj)     * 2304 + vd8);
        uint4 v1v = *(const uint4*)(vptr + (size_t)(2 * vj + 1) * 2304 + vd8);
        *(uint4*)(Ks + skey * 72 + sd)     = k0v;
        *(uint4*)(Ks + skey * 72 + sd + 8) = k1v;
        union { uint4 q; unsigned short u[8]; } u0, u1;
        u0.q = v0v; u1.q = v1v;
#pragma unroll
        for (int i = 0; i < 8; i++) {
            unsigned int w = (unsigned int)u0.u[i] | ((unsigned int)u1.u[i] << 16);
            *(unsigned int*)(Vt + (vd8 + i) * 72 + 2 * vj) = w;
        }
    }
    __syncthreads();

    for (int t = 0; t < SEQ / 64; t++) {
        // early prefetch of tile t+1 (in-flight across the whole compute phase)
        uint4 k0v, k1v, v0v, v1v;
        bool more = (t + 1 < SEQ / 64);
        if (more) {
            int kt = (t + 1) * 64;
            k0v = *(const uint4*)(kptr + (size_t)(kt + skey) * 2304 + sd);
            k1v = *(const uint4*)(kptr + (size_t)(kt + skey) * 2304 + sd + 8);
            v0v = *(const uint4*)(vptr + (size_t)(kt + 2 * vj)     * 2304 + vd8);
            v1v = *(const uint4*)(vptr + (size_t)(kt + 2 * vj + 1) * 2304 + vd8);
        }

        // S^T: st[ts][r] = score(key = ts*16 + quad*4 + r, qrow = l15)
        floatx4 st[4];
#pragma unroll
        for (int ts = 0; ts < 4; ts++) {
            floatx4 s = fz;
#pragma unroll
            for (int kk = 0; kk < 2; kk++) {
                short8 ak = *(const short8*)(Ks + (ts * 16 + l15) * 72 + kk * 32 + quad * 8);
                s = __builtin_amdgcn_mfma_f32_16x16x32_bf16(ak, bq[kk], s, 0, 0, 0);
            }
            st[ts] = s;
        }

        float tmax = st[0][0];
#pragma unroll
        for (int ts = 0; ts < 4; ts++)
#pragma unroll
            for (int r = 0; r < 4; r++) tmax = fmaxf(tmax, st[ts][r]);
        tmax = fmaxf(tmax, __shfl_xor(tmax, 16, 64));
        tmax = fmaxf(tmax, __shfl_xor(tmax, 32, 64));
        if (tmax > m) {
            float alpha = fast_exp2(m - tmax);
            m = tmax;
            lsum *= alpha;
#pragma unroll
            for (int dg = 0; dg < 4; dg++)
#pragma unroll
                for (int r = 0; r < 4; r++) o[dg][r] *= alpha;
        }
        float p[4][4];
        float ps = 0.f;
#pragma unroll
        for (int ts = 0; ts < 4; ts++)
#pragma unroll
            for (int r = 0; r < 4; r++) {
                p[ts][r] = fast_exp2(st[ts][r] - m);
                ps += p[ts][r];
            }
        lsum += ps;
#pragma unroll
        for (int ts = 0; ts < 4; ts++) {
            unsigned int w01 = __builtin_amdgcn_perm(fbits(p[ts][1]), fbits(p[ts][0]), 0x07060302);
            unsigned int w23 = __builtin_amdgcn_perm(fbits(p[ts][3]), fbits(p[ts][2]), 0x07060302);
            uint2 wv; wv.x = w01; wv.y = w23;
            *(uint2*)(Ps[wave] + l15 * 72 + ts * 16 + quad * 4) = wv;
        }

        // O^T += V^T P  (Ps wave-private: no barrier)
#pragma unroll
        for (int hk = 0; hk < 2; hk++) {
            short8 bp = *(const short8*)(Ps[wave] + l15 * 72 + hk * 32 + quad * 8);
#pragma unroll
            for (int dg = 0; dg < 4; dg++) {
                short8 av = *(const short8*)(Vt + (dg * 16 + l15) * 72 + hk * 32 + quad * 8);
                o[dg] = __builtin_amdgcn_mfma_f32_16x16x32_bf16(av, bp, o[dg], 0, 0, 0);
            }
        }

        __syncthreads();   // all waves done reading tile t
        if (more) {
            *(uint4*)(Ks + skey * 72 + sd)     = k0v;
            *(uint4*)(Ks + skey * 72 + sd + 8) = k1v;
            union { uint4 q; unsigned short u[8]; } u0, u1;
            u0.q = v0v; u1.q = v1v;
#pragma unroll
            for (int i = 0; i < 8; i++) {
                unsigned int w = (unsigned int)u0.u[i] | ((unsigned int)u1.u[i] << 16);
                *(unsigned int*)(Vt + (vd8 + i) * 72 + 2 * vj) = w;
            }
        }
        __syncthreads();   // tile t+1 visible
    }

    lsum += __shfl_xor(lsum, 16, 64);
    lsum += __shfl_xor(lsum, 32, 64);
    float inv = 1.f / lsum;
    size_t orow = ((size_t)b * SEQ + qbase + l15) * CDIM + h * 64;
#pragma unroll
    for (int dg = 0; dg < 4; dg++) {
        unsigned int u0 = (unsigned int)f2bf(o[dg][0] * inv) | ((unsigned int)f2bf(o[dg][1] * inv) << 16);
        unsigned int u1 = (unsigned int)f2bf(o[dg][2] * inv) | ((unsigned int)f2bf(o[dg][3] * inv) << 16);
        uint2 wv; wv.x = u0; wv.y = u1;
        *(uint2*)((unsigned short*)out + orow + dg * 16 + quad * 4) = wv;
    }
}

// ---------------------------------------------------------------------------
extern "C" void kernel_launch(void* const* d_in, const int* in_sizes, int n_in,
                              void* d_out, int out_size, void* d_ws, size_t ws_size,
                              hipStream_t stream)
{
    const float* x      = (const float*)d_in[0];
    const float* qkv_w  = (const float*)d_in[1];
    const float* proj_w = (const float*)d_in[2];
    const float* proj_b = (const float*)d_in[3];
    const float* n1w    = (const float*)d_in[4];
    const float* n1b    = (const float*)d_in[5];
    const float* n2w    = (const float*)d_in[6];
    const float* n2b    = (const float*)d_in[7];
    const float* fc1w   = (const float*)d_in[8];
    const float* fc1b   = (const float*)d_in[9];
    const float* fc2w   = (const float*)d_in[10];
    const float* fc2b   = (const float*)d_in[11];
    float* out = (float*)d_out;   // doubles as x2 (post-attn residual, fp32)

    unsigned short* ws = (unsigned short*)d_ws;
    unsigned short* wq = ws;                    // 1,769,472
    unsigned short* wp = wq + 1769472;          //   589,824
    unsigned short* w1 = wp + 589824;           // 2,359,296
    unsigned short* w2 = w1 + 2359296;          // 2,359,296
    unsigned short* h    = w2 + 2359296;        // 6,291,456
    unsigned short* qkv  = h + 6291456;         // 18,874,368
    unsigned short* attn = qkv + 18874368;      // 6,291,456
    unsigned short* a    = qkv;                 // fc1 out reuses qkv+attn

    dim3 blk(256);
    cvt_all_kernel<<<6912, blk, 0, stream>>>(qkv_w, proj_w, fc1w, fc2w, wq, wp, w1, w2);

    ln_kernel<<<NTOK / 4, blk, 0, stream>>>(x, n1w, n1b, h);
    gemm_bt<0, 0, 128><<<dim3(NTOK / 128, 2304 / 128), blk, 0, stream>>>(
        h, wq, nullptr, nullptr, qkv, NTOK, 2304, 768, 768, KS2);   // scale Q cols
    attn_kernel<<<dim3(SEQ / 64, NBAT * NH), blk, 0, stream>>>(qkv, attn);
    gemm_bt<0, 1, 64><<<dim3(NTOK / 64, 768 / 128), blk, 0, stream>>>(
        attn, wp, proj_b, x, out, NTOK, 768, 768, 0, 1.f);
    ln_kernel<<<NTOK / 4, blk, 0, stream>>>(out, n2w, n2b, h);
    gemm_bt<1, 0, 128><<<dim3(NTOK / 128, 3072 / 128), blk, 0, stream>>>(
        h, w1, fc1b, nullptr, a, NTOK, 3072, 768, 0, 1.f);
    gemm_bt<0, 1, 64><<<dim3(NTOK / 64, 768 / 128), blk, 0, stream>>>(
        a, w2, fc2b, out, out, NTOK, 768, 3072, 0, 1.f);
}

// Round 8
// 393.233 us; speedup vs baseline: 1.4743x; 1.0107x over previous
//
#include <hip/hip_runtime.h>
#include <hip/hip_bf16.h>

#define SEQ   2048
#define NBAT  4
#define NH    12
#define HD    64
#define CDIM  768
#define HID   3072
#define NTOK  (SEQ*NBAT)   // 8192 rows

#define KS2 0.1803368801111244f   // 0.125 * log2(e), folded into Q

typedef __attribute__((ext_vector_type(8))) short short8;   // 8 bf16 (4 VGPRs)
typedef __attribute__((ext_vector_type(4))) float floatx4;  // MFMA C/D

__device__ __forceinline__ float bf2f(unsigned short u) {
    union { unsigned int i; float f; } v; v.i = ((unsigned int)u) << 16; return v.f;
}
__device__ __forceinline__ unsigned short f2bf(float f) {
    union { float f; unsigned int i; } v; v.f = f;
    unsigned int i = v.i;
    return (unsigned short)((i + 0x7FFFu + ((i >> 16) & 1u)) >> 16);  // RNE
}
__device__ __forceinline__ unsigned int fbits(float f) {
    union { float f; unsigned int i; } v; v.f = f; return v.i;
}
__device__ __forceinline__ float fast_exp2(float x) {   // native v_exp_f32
#if __has_builtin(__builtin_amdgcn_exp2f)
    return __builtin_amdgcn_exp2f(x);
#else
    return __expf(x * 0.69314718055994531f);
#endif
}
__device__ __forceinline__ float fast_rcp(float x) {
#if __has_builtin(__builtin_amdgcn_rcpf)
    return __builtin_amdgcn_rcpf(x);
#else
    return 1.f / x;
#endif
}
// tanh-form GELU with native ops only
__device__ __forceinline__ float gelu_f(float v) {
    float u = 0.7978845608028654f * v * (1.f + 0.044715f * v * v);
    float e = fast_exp2(u * 2.885390081777927f);      // e^(2u)
    float th = 1.f - 2.f * fast_rcp(e + 1.f);         // tanh(u)
    return 0.5f * v * (1.f + th);
}
// async global->LDS, 16B/lane; LDS dest = wave-uniform base + lane*16B
__device__ __forceinline__ void gload16(const unsigned short* g, unsigned short* l) {
    __builtin_amdgcn_global_load_lds(
        (const __attribute__((address_space(1))) unsigned int*)g,
        (__attribute__((address_space(3))) unsigned int*)l, 16, 0, 0);
}

// ---------------------------------------------------------------------------
// fp32 -> bf16 conversion of all 4 weight matrices in ONE launch.
// ---------------------------------------------------------------------------
__global__ __launch_bounds__(256) void cvt_all_kernel(
    const float* __restrict__ s0, const float* __restrict__ s1,
    const float* __restrict__ s2, const float* __restrict__ s3,
    unsigned short* __restrict__ d0, unsigned short* __restrict__ d1,
    unsigned short* __restrict__ d2, unsigned short* __restrict__ d3)
{
    int blk = blockIdx.x;
    const float* src; unsigned short* dst; int off;
    if (blk < 1728)      { src = s0; dst = d0; off = blk; }
    else if (blk < 2304) { src = s1; dst = d1; off = blk - 1728; }
    else if (blk < 4608) { src = s2; dst = d2; off = blk - 2304; }
    else                 { src = s3; dst = d3; off = blk - 4608; }
    int i = (off * 256 + threadIdx.x) * 4;
    float4 f = *(const float4*)(src + i);
    ushort4 o;
    o.x = f2bf(f.x); o.y = f2bf(f.y); o.z = f2bf(f.z); o.w = f2bf(f.w);
    *(ushort4*)(dst + i) = o;
}

// ---------------------------------------------------------------------------
// LayerNorm: fp32 in, bf16 out. One wave per 768-elem row, float4 loads.
// ---------------------------------------------------------------------------
__global__ __launch_bounds__(256) void ln_kernel(
    const float* __restrict__ x, const float* __restrict__ w,
    const float* __restrict__ b, unsigned short* __restrict__ y)
{
    int row  = blockIdx.x * 4 + (threadIdx.x >> 6);
    int lane = threadIdx.x & 63;
    const float4* xr = (const float4*)(x + (size_t)row * CDIM);
    float4 v[3];
    float s = 0.f, sq = 0.f;
#pragma unroll
    for (int i = 0; i < 3; i++) {
        float4 f = xr[lane + i * 64];
        v[i] = f;
        s  += (f.x + f.y) + (f.z + f.w);
        sq += (f.x * f.x + f.y * f.y) + (f.z * f.z + f.w * f.w);
    }
#pragma unroll
    for (int o = 32; o > 0; o >>= 1) {
        s  += __shfl_xor(s,  o, 64);
        sq += __shfl_xor(sq, o, 64);
    }
    float mean = s * (1.f / CDIM);
    float var  = sq * (1.f / CDIM) - mean * mean;
    float rstd = rsqrtf(var + 1e-5f);
    const float4* w4 = (const float4*)w;
    const float4* b4 = (const float4*)b;
    ushort4* y4 = (ushort4*)(y + (size_t)row * CDIM);
#pragma unroll
    for (int i = 0; i < 3; i++) {
        int c = lane + i * 64;
        float4 wf = w4[c], bf_ = b4[c];
        ushort4 o;
        o.x = f2bf((v[i].x - mean) * rstd * wf.x + bf_.x);
        o.y = f2bf((v[i].y - mean) * rstd * wf.y + bf_.y);
        o.z = f2bf((v[i].z - mean) * rstd * wf.z + bf_.z);
        o.w = f2bf((v[i].w - mean) * rstd * wf.w + bf_.w);
        y4[c] = o;
    }
}

// ---------------------------------------------------------------------------
// GEMM: C[M,N] = act(A[M,K] @ W[N,K]^T + bias + residual), BK=64.
// Grid: x = M-tiles (fastest -> consecutive blocks share W-tile, L2 reuse).
// XOR-swizzled LDS staging: kchunk c of row r at LDS slot c ^ (r&7).
// ---------------------------------------------------------------------------
#define BK 64

template<int ACT, int OUT32, int TM>
__global__ __launch_bounds__(256) void gemm_bt(
    const unsigned short* __restrict__ A, const unsigned short* __restrict__ W,
    const float* __restrict__ bias, const float* __restrict__ res,
    void* __restrict__ Cv, int M, int N, int K, int scol, float scale)
{
    constexpr int MT   = TM / 32;      // M frags per wave (4 or 2)
    constexpr int ISSA = TM / 32;      // A gload issues per wave
    __shared__ __align__(16) unsigned short As[TM * BK];
    __shared__ __align__(16) unsigned short Bs[128 * BK];
    int tid  = threadIdx.x;
    int wave = tid >> 6, lane = tid & 63;
    int wr = wave >> 1, wc = wave & 1;
    int quad = lane >> 4, l15 = lane & 15;
    int m0 = blockIdx.x * TM, n0 = blockIdx.y * 128;

    int r8 = lane >> 3;                        // row-in-8 for staging
    int kc = (lane & 7) ^ r8;                  // swizzled source k-chunk
    const unsigned short* Ag = A + (size_t)(m0 + wave * (TM / 4) + r8) * K + kc * 8;
    const unsigned short* Wg = W + (size_t)(n0 + wave * 32 + r8) * K + kc * 8;
    unsigned short* AsW = As + wave * (TM / 4) * BK;
    unsigned short* BsW = Bs + wave * 32 * BK;

    floatx4 acc[MT][4];
    floatx4 fz = {0.f, 0.f, 0.f, 0.f};
#pragma unroll
    for (int i = 0; i < MT; i++)
#pragma unroll
        for (int j = 0; j < 4; j++) acc[i][j] = fz;

    int sw = l15 & 7;                          // read-side swizzle key
    for (int k0 = 0; k0 < K; k0 += BK) {
        __syncthreads();   // prior readers done before overwrite
#pragma unroll
        for (int j = 0; j < ISSA; j++)
            gload16(Ag + (size_t)(8 * j) * K + k0, AsW + j * 512);
#pragma unroll
        for (int j = 0; j < 4; j++)
            gload16(Wg + (size_t)(8 * j) * K + k0, BsW + j * 512);
        __syncthreads();   // drain: DMA visible

#pragma unroll
        for (int s = 0; s < 2; s++) {
            short8 af[MT], bfg[4];
            int ko = ((s * 4 + quad) ^ sw) * 8;   // swizzled k-offset
#pragma unroll
            for (int mt = 0; mt < MT; mt++)
                af[mt] = *(const short8*)(As + (wr * (TM / 2) + mt * 16 + l15) * BK + ko);
#pragma unroll
            for (int nt = 0; nt < 4; nt++)
                bfg[nt] = *(const short8*)(Bs + (wc * 64 + nt * 16 + l15) * BK + ko);
#pragma unroll
            for (int mt = 0; mt < MT; mt++)
#pragma unroll
                for (int nt = 0; nt < 4; nt++)
                    acc[mt][nt] = __builtin_amdgcn_mfma_f32_16x16x32_bf16(
                        af[mt], bfg[nt], acc[mt][nt], 0, 0, 0);
        }
    }

#pragma unroll
    for (int mt = 0; mt < MT; mt++) {
#pragma unroll
        for (int nt = 0; nt < 4; nt++) {
            int col = n0 + wc * 64 + nt * 16 + l15;
            float bv = bias ? bias[col] : 0.f;
            float cs = (col < scol) ? scale : 1.f;
#pragma unroll
            for (int r = 0; r < 4; r++) {
                int row = m0 + wr * (TM / 2) + mt * 16 + quad * 4 + r;
                size_t idx = (size_t)row * N + col;
                float v = acc[mt][nt][r] + bv;
                if (res) v += res[idx];
                if (ACT == 1) v = gelu_f(v);
                v *= cs;
                if (OUT32) ((float*)Cv)[idx] = v;
                else       ((unsigned short*)Cv)[idx] = f2bf(v);
            }
        }
    }
}

// ---------------------------------------------------------------------------
// Flash attention v5: 128 q/block (4 waves x 32 q as two 16-q halves).
// K/V LDS frag reads SHARED across the two q-halves (halves LDS traffic/q).
// K staged via swizzled global_load_lds DMA (dbuf); V manual transpose (dbuf);
// dual wave-private Ps buffers; ONE barrier per tile.
// ---------------------------------------------------------------------------
__global__ __launch_bounds__(256) void attn_kernel(
    const unsigned short* __restrict__ qkv, unsigned short* __restrict__ out)
{
    __shared__ __align__(16) unsigned short Ks[2][64 * 64];      // [key][d] swizzled
    __shared__ __align__(16) unsigned short Vt[2][64 * 72];      // [d][key]
    __shared__ __align__(16) unsigned short Ps[4][2][16 * 72];   // [wave][qh][qrow][key]

    int tid  = threadIdx.x;
    int wave = tid >> 6, lane = tid & 63;
    int quad = lane >> 4, l15 = lane & 15;
    int bh = blockIdx.y;
    int b  = bh / NH, h = bh % NH;
    size_t base = (size_t)b * SEQ * 2304 + h * 64;
    int qbase = blockIdx.x * 128 + wave * 32;

    // Q B-frags (pre-scaled by KS2 in qkv gemm): B[n=q][k=d]
    short8 bq[2][2];
#pragma unroll
    for (int qh = 0; qh < 2; qh++)
#pragma unroll
        for (int kk = 0; kk < 2; kk++)
            bq[qh][kk] = *(const short8*)(qkv + base +
                (size_t)(qbase + qh * 16 + l15) * 2304 + kk * 32 + quad * 8);

    floatx4 o[2][4];
    floatx4 fz = {0.f, 0.f, 0.f, 0.f};
#pragma unroll
    for (int qh = 0; qh < 2; qh++)
#pragma unroll
        for (int dg = 0; dg < 4; dg++) o[qh][dg] = fz;
    float m2[2] = {-3e38f, -3e38f};
    float ls[2] = {0.f, 0.f};

    // K DMA: wave stages keys wave*16..+15; lane -> row lane>>3, chunk (lane&7)^((lane>>3)&7)
    const unsigned short* kg = qkv + base + 768 +
        (size_t)(wave * 16 + (lane >> 3)) * 2304 + (((lane & 7) ^ ((lane >> 3) & 7)) * 8);
    // V staging: lane covers keys 2vj,2vj+1 at d-range vd8..vd8+7
    const unsigned short* vptr = qkv + base + 1536;
    int vj  = tid & 31;
    int vd8 = wave * 16 + ((tid >> 5) & 1) * 8;
    int sw  = l15 & 7;   // K read swizzle key

    // prologue: tile 0
    gload16(kg, &Ks[0][wave * 1024]);
    gload16(kg + (size_t)8 * 2304, &Ks[0][wave * 1024 + 512]);
    {
        uint4 v0v = *(const uint4*)(vptr + (size_t)(2 * vj)     * 2304 + vd8);
        uint4 v1v = *(const uint4*)(vptr + (size_t)(2 * vj + 1) * 2304 + vd8);
        union { uint4 q; unsigned short u[8]; } u0, u1;
        u0.q = v0v; u1.q = v1v;
#pragma unroll
        for (int i = 0; i < 8; i++) {
            unsigned int w = (unsigned int)u0.u[i] | ((unsigned int)u1.u[i] << 16);
            *(unsigned int*)(&Vt[0][(vd8 + i) * 72 + 2 * vj]) = w;
        }
    }
    __syncthreads();

    for (int t = 0; t < SEQ / 64; t++) {
        int cur = t & 1, nxt = cur ^ 1;
        bool more = (t + 1 < SEQ / 64);
        uint4 v0v, v1v;
        if (more) {   // prefetch t+1: K straight to LDS (dbuf), V to regs
            const unsigned short* kg2 = kg + (size_t)(t + 1) * 64 * 2304;
            gload16(kg2, &Ks[nxt][wave * 1024]);
            gload16(kg2 + (size_t)8 * 2304, &Ks[nxt][wave * 1024 + 512]);
            int kt = (t + 1) * 64;
            v0v = *(const uint4*)(vptr + (size_t)(kt + 2 * vj)     * 2304 + vd8);
            v1v = *(const uint4*)(vptr + (size_t)(kt + 2 * vj + 1) * 2304 + vd8);
        }

        // S^T for both q-halves; K frags read ONCE, shared.
        floatx4 st[2][4];
#pragma unroll
        for (int ts = 0; ts < 4; ts++) {
            short8 ak0 = *(const short8*)(&Ks[cur][(ts * 16 + l15) * 64 + (((0 * 4 + quad) ^ sw) * 8)]);
            short8 ak1 = *(const short8*)(&Ks[cur][(ts * 16 + l15) * 64 + (((1 * 4 + quad) ^ sw) * 8)]);
            floatx4 s0 = __builtin_amdgcn_mfma_f32_16x16x32_bf16(ak0, bq[0][0], fz, 0, 0, 0);
            s0 = __builtin_amdgcn_mfma_f32_16x16x32_bf16(ak1, bq[0][1], s0, 0, 0, 0);
            floatx4 s1 = __builtin_amdgcn_mfma_f32_16x16x32_bf16(ak0, bq[1][0], fz, 0, 0, 0);
            s1 = __builtin_amdgcn_mfma_f32_16x16x32_bf16(ak1, bq[1][1], s1, 0, 0, 0);
            st[0][ts] = s0; st[1][ts] = s1;
        }

        // online softmax per q-half; P -> Ps[wave][qh]
#pragma unroll
        for (int qh = 0; qh < 2; qh++) {
            float tmax = st[qh][0][0];
#pragma unroll
            for (int ts = 0; ts < 4; ts++)
#pragma unroll
                for (int r = 0; r < 4; r++) tmax = fmaxf(tmax, st[qh][ts][r]);
            tmax = fmaxf(tmax, __shfl_xor(tmax, 16, 64));
            tmax = fmaxf(tmax, __shfl_xor(tmax, 32, 64));
            if (tmax > m2[qh]) {
                float alpha = fast_exp2(m2[qh] - tmax);
                m2[qh] = tmax;
                ls[qh] *= alpha;
#pragma unroll
                for (int dg = 0; dg < 4; dg++)
#pragma unroll
                    for (int r = 0; r < 4; r++) o[qh][dg][r] *= alpha;
            }
            float mm = m2[qh];
            float psum = 0.f;
#pragma unroll
            for (int ts = 0; ts < 4; ts++) {
                float p0 = fast_exp2(st[qh][ts][0] - mm);
                float p1 = fast_exp2(st[qh][ts][1] - mm);
                float p2 = fast_exp2(st[qh][ts][2] - mm);
                float p3 = fast_exp2(st[qh][ts][3] - mm);
                psum += (p0 + p1) + (p2 + p3);
                unsigned int w01 = __builtin_amdgcn_perm(fbits(p1), fbits(p0), 0x07060302);
                unsigned int w23 = __builtin_amdgcn_perm(fbits(p3), fbits(p2), 0x07060302);
                uint2 wv; wv.x = w01; wv.y = w23;
                *(uint2*)(&Ps[wave][qh][l15 * 72 + ts * 16 + quad * 4]) = wv;
            }
            ls[qh] += psum;
        }

        // O^T += V^T P for both q-halves; V frags read ONCE, shared.
#pragma unroll
        for (int hk = 0; hk < 2; hk++) {
            short8 bp0 = *(const short8*)(&Ps[wave][0][l15 * 72 + hk * 32 + quad * 8]);
            short8 bp1 = *(const short8*)(&Ps[wave][1][l15 * 72 + hk * 32 + quad * 8]);
#pragma unroll
            for (int dg = 0; dg < 4; dg++) {
                short8 av = *(const short8*)(&Vt[cur][(dg * 16 + l15) * 72 + hk * 32 + quad * 8]);
                o[0][dg] = __builtin_amdgcn_mfma_f32_16x16x32_bf16(av, bp0, o[0][dg], 0, 0, 0);
                o[1][dg] = __builtin_amdgcn_mfma_f32_16x16x32_bf16(av, bp1, o[1][dg], 0, 0, 0);
            }
        }

        // stage V(t+1)
        if (more) {
            union { uint4 q; unsigned short u[8]; } u0, u1;
            u0.q = v0v; u1.q = v1v;
#pragma unroll
            for (int i = 0; i < 8; i++) {
                unsigned int w = (unsigned int)u0.u[i] | ((unsigned int)u1.u[i] << 16);
                *(unsigned int*)(&Vt[nxt][(vd8 + i) * 72 + 2 * vj]) = w;
            }
        }
        __syncthreads();   // drains vmcnt(0): K-DMA(t+1) + all LDS writes visible
    }

#pragma unroll
    for (int qh = 0; qh < 2; qh++) {
        float l = ls[qh];
        l += __shfl_xor(l, 16, 64);
        l += __shfl_xor(l, 32, 64);
        float inv = 1.f / l;
        size_t orow = ((size_t)b * SEQ + qbase + qh * 16 + l15) * CDIM + h * 64;
#pragma unroll
        for (int dg = 0; dg < 4; dg++) {
            unsigned int u0 = (unsigned int)f2bf(o[qh][dg][0] * inv) | ((unsigned int)f2bf(o[qh][dg][1] * inv) << 16);
            unsigned int u1 = (unsigned int)f2bf(o[qh][dg][2] * inv) | ((unsigned int)f2bf(o[qh][dg][3] * inv) << 16);
            uint2 wv; wv.x = u0; wv.y = u1;
            *(uint2*)((unsigned short*)out + orow + dg * 16 + quad * 4) = wv;
        }
    }
}

// ---------------------------------------------------------------------------
extern "C" void kernel_launch(void* const* d_in, const int* in_sizes, int n_in,
                              void* d_out, int out_size, void* d_ws, size_t ws_size,
                              hipStream_t stream)
{
    const float* x      = (const float*)d_in[0];
    const float* qkv_w  = (const float*)d_in[1];
    const float* proj_w = (const float*)d_in[2];
    const float* proj_b = (const float*)d_in[3];
    const float* n1w    = (const float*)d_in[4];
    const float* n1b    = (const float*)d_in[5];
    const float* n2w    = (const float*)d_in[6];
    const float* n2b    = (const float*)d_in[7];
    const float* fc1w   = (const float*)d_in[8];
    const float* fc1b   = (const float*)d_in[9];
    const float* fc2w   = (const float*)d_in[10];
    const float* fc2b   = (const float*)d_in[11];
    float* out = (float*)d_out;   // doubles as x2 (post-attn residual, fp32)

    unsigned short* ws = (unsigned short*)d_ws;
    unsigned short* wq = ws;                    // 1,769,472
    unsigned short* wp = wq + 1769472;          //   589,824
    unsigned short* w1 = wp + 589824;           // 2,359,296
    unsigned short* w2 = w1 + 2359296;          // 2,359,296
    unsigned short* h    = w2 + 2359296;        // 6,291,456
    unsigned short* qkv  = h + 6291456;         // 18,874,368
    unsigned short* attn = qkv + 18874368;      // 6,291,456
    unsigned short* a    = qkv;                 // fc1 out reuses qkv+attn

    dim3 blk(256);
    cvt_all_kernel<<<6912, blk, 0, stream>>>(qkv_w, proj_w, fc1w, fc2w, wq, wp, w1, w2);

    ln_kernel<<<NTOK / 4, blk, 0, stream>>>(x, n1w, n1b, h);
    gemm_bt<0, 0, 128><<<dim3(NTOK / 128, 2304 / 128), blk, 0, stream>>>(
        h, wq, nullptr, nullptr, qkv, NTOK, 2304, 768, 768, KS2);   // scale Q cols
    attn_kernel<<<dim3(SEQ / 128, NBAT * NH), blk, 0, stream>>>(qkv, attn);
    gemm_bt<0, 1, 64><<<dim3(NTOK / 64, 768 / 128), blk, 0, stream>>>(
        attn, wp, proj_b, x, out, NTOK, 768, 768, 0, 1.f);
    ln_kernel<<<NTOK / 4, blk, 0, stream>>>(out, n2w, n2b, h);
    gemm_bt<1, 0, 128><<<dim3(NTOK / 128, 3072 / 128), blk, 0, stream>>>(
        h, w1, fc1b, nullptr, a, NTOK, 3072, 768, 0, 1.f);
    gemm_bt<0, 1, 64><<<dim3(NTOK / 64, 768 / 128), blk, 0, stream>>>(
        a, w2, fc2b, out, out, NTOK, 768, 3072, 0, 1.f);
}